// Round 7
// baseline (1580.702 us; speedup 1.0000x reference)
//
#include <hip/hip_runtime.h>

// Orthonorm: Y = X * (sqrt(512) * inv(chol(X^T X + eps I))^T)
// X: [262144, 512] fp32.  Heavy matmuls via bf16 MFMA (fp32 accum).
// r7: gram_k1 fuses fp32->bf16 convert with off-diag gram tile (X read once);
// gram_k2 does diag tiles from bf16.  chol_step merges diag-factor + panel
// trsm via redundant per-block diag computation (15 -> 8 dispatches).
// ymm5 = dbuf + counted s_waitcnt vmcnt(4) + raw s_barrier (T4 pattern --
// next-tile global_load_lds stays in flight across the barrier).

#define EPSJ 1e-6f
#define SQRTD 22.627416997969522f

typedef short bf16x8 __attribute__((ext_vector_type(8)));
typedef float f32x4 __attribute__((ext_vector_type(4)));

__device__ __forceinline__ unsigned short f2bf(float f) {
  unsigned u = __float_as_uint(f);
  unsigned r = u + 0x7fffu + ((u >> 16) & 1u);   // RNE
  return (unsigned short)(r >> 16);
}

// 16B-slot XOR swizzle within a 128B LDS row (8 slots). Involution in slot.
__device__ __forceinline__ int swz(int row, int slot) {
  return slot ^ ((row ^ (row >> 3)) & 7);
}

#define GLOAD16(g, l)                                                         \
  __builtin_amdgcn_global_load_lds(                                           \
      (const __attribute__((address_space(1))) void*)(g),                     \
      (__attribute__((address_space(3))) void*)(l), 16, 0, 0)

// ---------------------------------------------------------------------------
// Kernel 1a: off-diag gram tile (0,256) from fp32 X + emit Xbf.
// grid = nchunk x 512.  Thread (kg = t>>6 in 0..7, c = t&63): rows kg*8..+7,
// cols c*8..c*8+7.  c<32 -> As half (cols 0..255), else Bs (256..511).
// ---------------------------------------------------------------------------
__global__ __launch_bounds__(512, 2) void gram_k1(
    const float* __restrict__ X, unsigned short* __restrict__ Xbf,
    float* __restrict__ part, int nchunk) {
  __shared__ unsigned short As[256 * 64];
  __shared__ unsigned short Bs[256 * 64];
  const int b = blockIdx.x;
  const int s0 = (int)((long)4096 * b / nchunk);
  const int s1 = (int)((long)4096 * (b + 1) / nchunk);
  const int t = threadIdx.x, lane = t & 63, w = t >> 6;
  const int wr = w >> 2, wc = w & 3;
  const int kg = t >> 6;           // 0..7
  const int c = t & 63;            // col octet 0..63
  unsigned short* half = (c < 32) ? As : Bs;
  const int cl = (c & 31) * 8;     // local col base

  f32x4 acc[8][4];
  const f32x4 zf = {0.f, 0.f, 0.f, 0.f};
  #pragma unroll
  for (int a = 0; a < 8; ++a)
    #pragma unroll
    for (int bb = 0; bb < 4; ++bb) acc[a][bb] = zf;

  for (int ks = s0; ks < s1; ++ks) {
    long r0 = (long)ks * 64 + kg * 8;
    const float* src = X + r0 * 512 + c * 8;
    uint4 rp[8];
    #pragma unroll
    for (int rr = 0; rr < 8; ++rr) {
      float4 f0 = *(const float4*)(src + rr * 512);
      float4 f1 = *(const float4*)(src + rr * 512 + 4);
      rp[rr].x = (unsigned)f2bf(f0.x) | ((unsigned)f2bf(f0.y) << 16);
      rp[rr].y = (unsigned)f2bf(f0.z) | ((unsigned)f2bf(f0.w) << 16);
      rp[rr].z = (unsigned)f2bf(f1.x) | ((unsigned)f2bf(f1.y) << 16);
      rp[rr].w = (unsigned)f2bf(f1.z) | ((unsigned)f2bf(f1.w) << 16);
      *(uint4*)(Xbf + (r0 + rr) * 512 + c * 8) = rp[rr];
    }
    // transpose 8x8 to col-major k-packs, swizzled ds_write_b128 per col
    #pragma unroll
    for (int s = 0; s < 8; ++s) {
      unsigned v[8];
      #pragma unroll
      for (int rr = 0; rr < 8; ++rr) {
        unsigned word = (s & 4) ? ((s & 2) ? rp[rr].w : rp[rr].z)
                                : ((s & 2) ? rp[rr].y : rp[rr].x);
        v[rr] = (s & 1) ? (word >> 16) : (word & 0xFFFFu);
      }
      uint4 o = make_uint4(v[0] | (v[1] << 16), v[2] | (v[3] << 16),
                           v[4] | (v[5] << 16), v[6] | (v[7] << 16));
      int cc = cl + s;
      int sl = kg ^ ((cc ^ (cc >> 3)) & 7);
      *(uint4*)((char*)half + cc * 128 + sl * 16) = o;
    }
    __syncthreads();
    #pragma unroll
    for (int kk = 0; kk < 2; ++kk) {
      bf16x8 af[8], bfr[4];
      #pragma unroll
      for (int fm = 0; fm < 8; ++fm) {
        int row = wr * 128 + fm * 16 + (lane & 15);
        af[fm] = *(const bf16x8*)((const char*)As + row * 128 +
                                  swz(row, kk * 4 + (lane >> 4)) * 16);
      }
      #pragma unroll
      for (int fn = 0; fn < 4; ++fn) {
        int row = wc * 64 + fn * 16 + (lane & 15);
        bfr[fn] = *(const bf16x8*)((const char*)Bs + row * 128 +
                                   swz(row, kk * 4 + (lane >> 4)) * 16);
      }
      #pragma unroll
      for (int fm = 0; fm < 8; ++fm)
        #pragma unroll
        for (int fn = 0; fn < 4; ++fn)
          acc[fm][fn] = __builtin_amdgcn_mfma_f32_16x16x32_bf16(
              bfr[fn], af[fm], acc[fm][fn], 0, 0, 0);   // swapped
    }
    __syncthreads();
  }
  float* out = part + (long)(b * 3 + 2) * 65536;
  #pragma unroll
  for (int fm = 0; fm < 8; ++fm)
    #pragma unroll
    for (int fn = 0; fn < 4; ++fn) {
      int mi = wr * 128 + fm * 16 + (lane & 15);
      int nj = wc * 64 + fn * 16 + (lane >> 4) * 4;
      *(float4*)(out + mi * 256 + nj) = *(float4*)&acc[fm][fn];
    }
}

// ---------------------------------------------------------------------------
// Kernel 1b: diag gram tiles from bf16 Xbf. grid = 2*nchunk x 512.
// pos = b&1: (0,0) or (256,256).  Paired-row b64 pack staging.
// ---------------------------------------------------------------------------
__device__ __forceinline__ void stage_pack4(
    const unsigned short* __restrict__ src, unsigned short* dst, int c0,
    int kg) {
  uint4 r0 = *(const uint4*)src;
  uint4 r1 = *(const uint4*)(src + 512);
  uint4 r2 = *(const uint4*)(src + 1024);
  uint4 r3 = *(const uint4*)(src + 1536);
  unsigned a[4] = {r0.x, r0.y, r0.z, r0.w};
  unsigned b[4] = {r1.x, r1.y, r1.z, r1.w};
  unsigned c[4] = {r2.x, r2.y, r2.z, r2.w};
  unsigned d[4] = {r3.x, r3.y, r3.z, r3.w};
  const int khi = kg >> 1, koff = (kg & 1) * 8;
  #pragma unroll
  for (int s = 0; s < 8; ++s) {
    int wsel = s >> 1, sh = (s & 1) * 16;
    unsigned v0 = (a[wsel] >> sh) & 0xFFFFu;
    unsigned v1 = (b[wsel] >> sh) & 0xFFFFu;
    unsigned v2 = (c[wsel] >> sh) & 0xFFFFu;
    unsigned v3 = (d[wsel] >> sh) & 0xFFFFu;
    int cc = c0 + s;
    int sl = khi ^ ((cc ^ (cc >> 3)) & 7);
    *(uint2*)((char*)dst + cc * 128 + sl * 16 + koff) =
        make_uint2(v0 | (v1 << 16), v2 | (v3 << 16));
  }
}

__global__ __launch_bounds__(512, 2) void gram_k2(
    const unsigned short* __restrict__ Xbf, float* __restrict__ part,
    int nchunk) {
  __shared__ unsigned short As[256 * 64];
  const int b = blockIdx.x, pos = b & 1, chunk = b >> 1;
  const int s0 = (int)((long)4096 * chunk / nchunk);
  const int s1 = (int)((long)4096 * (chunk + 1) / nchunk);
  const int ca = pos ? 256 : 0;
  const int t = threadIdx.x, lane = t & 63, w = t >> 6;
  const int wr = w >> 2, wc = w & 3;

  f32x4 acc[8][4];
  const f32x4 zf = {0.f, 0.f, 0.f, 0.f};
  #pragma unroll
  for (int a = 0; a < 8; ++a)
    #pragma unroll
    for (int bb = 0; bb < 4; ++bb) acc[a][bb] = zf;

  const int c0 = (t & 31) * 8;
  const int kg = t >> 5;   // 0..15, rows kg*4..+3

  for (int ks = s0; ks < s1; ++ks) {
    long r = (long)ks * 64 + kg * 4;
    stage_pack4(Xbf + r * 512 + ca + c0, As, c0, kg);
    __syncthreads();
    #pragma unroll
    for (int kk = 0; kk < 2; ++kk) {
      bf16x8 af[8], bfr[4];
      #pragma unroll
      for (int fm = 0; fm < 8; ++fm) {
        int row = wr * 128 + fm * 16 + (lane & 15);
        af[fm] = *(const bf16x8*)((const char*)As + row * 128 +
                                  swz(row, kk * 4 + (lane >> 4)) * 16);
      }
      #pragma unroll
      for (int fn = 0; fn < 4; ++fn) {
        int row = wc * 64 + fn * 16 + (lane & 15);
        bfr[fn] = *(const bf16x8*)((const char*)As + row * 128 +
                                   swz(row, kk * 4 + (lane >> 4)) * 16);
      }
      #pragma unroll
      for (int fm = 0; fm < 8; ++fm)
        #pragma unroll
        for (int fn = 0; fn < 4; ++fn)
          acc[fm][fn] = __builtin_amdgcn_mfma_f32_16x16x32_bf16(
              bfr[fn], af[fm], acc[fm][fn], 0, 0, 0);   // swapped
    }
    __syncthreads();
  }
  float* out = part + (long)(chunk * 3 + pos) * 65536;
  #pragma unroll
  for (int fm = 0; fm < 8; ++fm)
    #pragma unroll
    for (int fn = 0; fn < 4; ++fn) {
      int mi = wr * 128 + fm * 16 + (lane & 15);
      int nj = wc * 64 + fn * 16 + (lane >> 4) * 4;
      *(float4*)(out + mi * 256 + nj) = *(float4*)&acc[fm][fn];
    }
}

// ---------------------------------------------------------------------------
// Kernel 1c (fallback, small ws): Gram partials from fp32 X.
// ---------------------------------------------------------------------------
__global__ __launch_bounds__(512, 2) void gram_f32(
    const float* __restrict__ X, float* __restrict__ part, int nchunk) {
  __shared__ unsigned short As[256 * 64];
  __shared__ unsigned short Bs[256 * 64];
  const int b = blockIdx.x;
  const int pos = b % 3;
  const int chunk = b / 3;
  const int CR = 262144 / nchunk;
  const long r0 = (long)chunk * CR;
  const int ca = (pos == 1) ? 256 : 0;
  const int cb = (pos == 0) ? 0 : 256;
  const bool diag = (pos != 2);
  const int t = threadIdx.x, lane = t & 63, w = t >> 6;
  const int wr = w >> 2, wc = w & 3;

  f32x4 acc[8][4];
  const f32x4 zf = {0.f, 0.f, 0.f, 0.f};
  #pragma unroll
  for (int a = 0; a < 8; ++a)
    #pragma unroll
    for (int bb = 0; bb < 4; ++bb) acc[a][bb] = zf;

  const int c_oct = t & 31, msub = t >> 5;

  for (int ks = 0; ks < CR; ks += 64) {
    #pragma unroll
    for (int it = 0; it < 4; ++it) {
      int m = msub + 16 * it;
      long row = r0 + ks + m;
      const float4* sa = (const float4*)(X + row * 512 + ca + c_oct * 8);
      float4 a0 = sa[0], a1 = sa[1];
      {
        float v[8] = {a0.x, a0.y, a0.z, a0.w, a1.x, a1.y, a1.z, a1.w};
        #pragma unroll
        for (int s = 0; s < 8; ++s) {
          int cc = c_oct * 8 + s;
          int off = cc * 128 + ((2 * m) ^ (((cc ^ (cc >> 3)) & 7) << 4));
          *(unsigned short*)((char*)As + off) = f2bf(v[s]);
        }
      }
      if (!diag) {
        const float4* sb = (const float4*)(X + row * 512 + cb + c_oct * 8);
        float4 b0 = sb[0], b1 = sb[1];
        float v[8] = {b0.x, b0.y, b0.z, b0.w, b1.x, b1.y, b1.z, b1.w};
        #pragma unroll
        for (int s = 0; s < 8; ++s) {
          int cc = c_oct * 8 + s;
          int off = cc * 128 + ((2 * m) ^ (((cc ^ (cc >> 3)) & 7) << 4));
          *(unsigned short*)((char*)Bs + off) = f2bf(v[s]);
        }
      }
    }
    __syncthreads();
    const unsigned short* Bp = diag ? As : Bs;
    #pragma unroll
    for (int kk = 0; kk < 2; ++kk) {
      bf16x8 af[8], bfr[4];
      #pragma unroll
      for (int fm = 0; fm < 8; ++fm) {
        int row = wr * 128 + fm * 16 + (lane & 15);
        af[fm] = *(const bf16x8*)((const char*)As + row * 128 +
                                  swz(row, kk * 4 + (lane >> 4)) * 16);
      }
      #pragma unroll
      for (int fn = 0; fn < 4; ++fn) {
        int row = wc * 64 + fn * 16 + (lane & 15);
        bfr[fn] = *(const bf16x8*)((const char*)Bp + row * 128 +
                                   swz(row, kk * 4 + (lane >> 4)) * 16);
      }
      #pragma unroll
      for (int fm = 0; fm < 8; ++fm)
        #pragma unroll
        for (int fn = 0; fn < 4; ++fn)
          acc[fm][fn] = __builtin_amdgcn_mfma_f32_16x16x32_bf16(
              bfr[fn], af[fm], acc[fm][fn], 0, 0, 0);   // swapped
    }
    __syncthreads();
  }
  float* out = part + (long)b * 65536;
  #pragma unroll
  for (int fm = 0; fm < 8; ++fm)
    #pragma unroll
    for (int fn = 0; fn < 4; ++fn) {
      int mi = wr * 128 + fm * 16 + (lane & 15);
      int nj = wc * 64 + fn * 16 + (lane >> 4) * 4;
      *(float4*)(out + mi * 256 + nj) = *(float4*)&acc[fm][fn];
    }
}

// ---------------------------------------------------------------------------
// Kernel 2: reduce partials -> full symmetric G [512][512] fp32. grid 768x256
// ---------------------------------------------------------------------------
__global__ void gram_reduce(const float* __restrict__ part,
                            float* __restrict__ G, int nchunk) {
  int idx = blockIdx.x * 256 + threadIdx.x;   // < 196608
  int pos = idx >> 16;
  int e = idx & 65535;
  float s = 0.f;
  for (int ch = 0; ch < nchunk; ++ch)
    s += part[(long)(ch * 3 + pos) * 65536 + e];
  int i = e >> 8, j = e & 255;
  if (pos == 0) {
    G[i * 512 + j] = s;
  } else if (pos == 1) {
    G[(256 + i) * 512 + 256 + j] = s;
  } else {
    G[i * 512 + 256 + j] = s;
    G[(256 + j) * 512 + i] = s;
  }
}

// ---------------------------------------------------------------------------
// Kernel 3: merged chol step p.  grid (8-p) x 256.
// ALL blocks redundantly: Pb = G[p][p]+epsI - SYRK(r<p); factor; Dinv_p=Inv.
// Block 0: publish Dinv_p.  Block b>0: tile i=p+b trsm-as-GEMM:
//   L[i][p] = (G[i][p] - sum_{r<p} L[i][r] L[p][r]^T) * Inv^T  -> G[i][p].
// No races: writes are G[i][p] (col p, distinct i) + Dinv[p]; all intra-step
// reads are cols r<p or raw diag.  G's diag blocks are never consumed
// (tri_assemble uses Dinv + off-diag L only).
// ---------------------------------------------------------------------------
__global__ __launch_bounds__(256) void chol_step(float* __restrict__ G,
                                                 float* __restrict__ Dinv,
                                                 int p) {
  __shared__ float Pb[64][65];
  __shared__ float Sb[64][65];
  __shared__ float Inv[64][65];
  __shared__ float SbP[64][65];
  __shared__ float Ub[64][65];
  __shared__ float Tt[32][33];
  const int t = threadIdx.x;
  const int r0 = 64 * p;
  const int tr = (t >> 4) * 4, tc = (t & 15) * 4;

  for (int idx = t; idx < 4096; idx += 256) {
    int i = idx >> 6, j = idx & 63;
    float v = G[(long)(r0 + i) * 512 + r0 + j];
    if (i == j) v += EPSJ;
    Pb[i][j] = v;
  }
  __syncthreads();

  if (p > 0) {
    float cc[4][4] = {{0.f}};
    for (int r = 0; r < p; ++r) {
      for (int idx = t; idx < 4096; idx += 256) {
        int i = idx >> 6, j = idx & 63;
        Sb[i][j] = G[(long)(r0 + i) * 512 + 64 * r + j];
      }
      __syncthreads();
      #pragma unroll 4
      for (int k = 0; k < 64; ++k) {
        float a0 = Sb[tr][k], a1 = Sb[tr+1][k], a2 = Sb[tr+2][k], a3 = Sb[tr+3][k];
        float b0 = Sb[tc][k], b1 = Sb[tc+1][k], b2 = Sb[tc+2][k], b3 = Sb[tc+3][k];
        cc[0][0]+=a0*b0; cc[0][1]+=a0*b1; cc[0][2]+=a0*b2; cc[0][3]+=a0*b3;
        cc[1][0]+=a1*b0; cc[1][1]+=a1*b1; cc[1][2]+=a1*b2; cc[1][3]+=a1*b3;
        cc[2][0]+=a2*b0; cc[2][1]+=a2*b1; cc[2][2]+=a2*b2; cc[2][3]+=a2*b3;
        cc[3][0]+=a3*b0; cc[3][1]+=a3*b1; cc[3][2]+=a3*b2; cc[3][3]+=a3*b3;
      }
      __syncthreads();
    }
    #pragma unroll
    for (int u = 0; u < 4; ++u)
      #pragma unroll
      for (int v = 0; v < 4; ++v)
        Pb[tr + u][tc + v] -= cc[u][v];
    __syncthreads();
  }

  const int lane = t & 63, w = t >> 6;
  #pragma unroll
  for (int sp = 0; sp < 2; ++sp) {
    const int b0 = sp * 32;
    if (w == 0) {                       // 32-col register factor (proven)
      float rr[32];
      #pragma unroll
      for (int k = 0; k < 32; ++k)
        rr[k] = (lane < 32) ? Pb[b0 + lane][b0 + k] : 0.f;
      #pragma unroll
      for (int j = 0; j < 32; ++j) {
        float d = sqrtf(__shfl(rr[j], j));
        if (lane == j) rr[j] = d;
        else if (lane > j && lane < 32) rr[j] = rr[j] / d;
        float rj = rr[j];
        #pragma unroll
        for (int k = j + 1; k < 32; ++k) {
          float Lkj = __shfl(rj, k);
          if (lane > j && lane < 32) rr[k] -= rj * Lkj;
        }
      }
      #pragma unroll
      for (int k = 0; k < 32; ++k)
        if (lane < 32) Pb[b0 + lane][b0 + k] = rr[k];
    }
    __syncthreads();
    if (sp == 0) {
      if (t < 32) {                     // solve rows 32..63 vs A (proven)
        int rw = 32 + t;
        float x[32];
        #pragma unroll
        for (int j = 0; j < 32; ++j) x[j] = Pb[rw][j];
        #pragma unroll
        for (int j = 0; j < 32; ++j) {
          float xj = x[j] / Pb[j][j];
          x[j] = xj;
          #pragma unroll
          for (int k2 = j + 1; k2 < 32; ++k2) x[k2] -= xj * Pb[k2][j];
        }
        #pragma unroll
        for (int j = 0; j < 32; ++j) Pb[rw][j] = x[j];
      }
      __syncthreads();
      {                                 // trailing 32x32 -= S S^T
        int i = 32 + (t >> 3), kb = 32 + (t & 7) * 4;
        float sv[4];
        #pragma unroll
        for (int e = 0; e < 4; ++e) sv[e] = Pb[i][kb + e];
        #pragma unroll 4
        for (int j = 0; j < 32; ++j) {
          float aij = Pb[i][j];
          #pragma unroll
          for (int e = 0; e < 4; ++e) sv[e] -= aij * Pb[kb + e][j];
        }
        #pragma unroll
        for (int e = 0; e < 4; ++e) Pb[i][kb + e] = sv[e];
      }
      __syncthreads();
    }
  }

  // invert A (0..31) and C (32..63): 64 parallel column solves (x[32])
  if (t < 64) {
    int col = t & 31, o = (t >> 5) * 32;
    float x[32];
    #pragma unroll
    for (int i = 0; i < 32; ++i) {
      float s = (i == col) ? 1.f : 0.f;
      #pragma unroll
      for (int j = 0; j < i; ++j) s -= Pb[o + i][o + j] * x[j];
      x[i] = s / Pb[o + i][o + i];
    }
    #pragma unroll
    for (int i = 0; i < 32; ++i) Inv[o + i][o + col] = x[i];
  }
  for (int idx = t; idx < 1024; idx += 256)      // zero top-right quadrant
    Inv[idx >> 5][32 + (idx & 31)] = 0.f;
  __syncthreads();
  {                                              // T1 = B * A^{-1}
    int i = t >> 3, jb = (t & 7) * 4;
    float sv[4] = {0.f, 0.f, 0.f, 0.f};
    #pragma unroll 4
    for (int k = 0; k < 32; ++k) {
      float bik = Pb[32 + i][k];
      #pragma unroll
      for (int e = 0; e < 4; ++e) sv[e] += bik * Inv[k][jb + e];
    }
    #pragma unroll
    for (int e = 0; e < 4; ++e) Tt[i][jb + e] = sv[e];
  }
  __syncthreads();
  {                                              // BL = -C^{-1} * T1
    int i = t >> 3, jb = (t & 7) * 4;
    float sv[4] = {0.f, 0.f, 0.f, 0.f};
    #pragma unroll 4
    for (int k = 0; k < 32; ++k) {
      float cik = Inv[32 + i][32 + k];
      #pragma unroll
      for (int e = 0; e < 4; ++e) sv[e] += cik * Tt[k][jb + e];
    }
    #pragma unroll
    for (int e = 0; e < 4; ++e) Inv[32 + i][jb + e] = -sv[e];
  }
  __syncthreads();

  if (blockIdx.x == 0) {
    for (int idx = t; idx < 4096; idx += 256)
      Dinv[p * 4096 + idx] = Inv[idx >> 6][idx & 63];
    return;
  }

  // ---- t-phase: tile i = p + blockIdx.x ----
  const long rI = 64 * (p + blockIdx.x), cP = 64 * p;
  float cc2[4][4] = {{0.f}};
  for (int r = 0; r < p; ++r) {
    __syncthreads();
    for (int idx = t; idx < 4096; idx += 256) {
      int i = idx >> 6, j = idx & 63;
      Sb[i][j] = G[(rI + i) * 512 + 64 * r + j];
      SbP[i][j] = G[(cP + i) * 512 + 64 * r + j];
    }
    __syncthreads();
    #pragma unroll 4
    for (int k = 0; k < 64; ++k) {
      float a0 = Sb[tr][k], a1 = Sb[tr+1][k], a2 = Sb[tr+2][k], a3 = Sb[tr+3][k];
      float b0 = SbP[tc][k], b1 = SbP[tc+1][k], b2 = SbP[tc+2][k], b3 = SbP[tc+3][k];
      cc2[0][0]+=a0*b0; cc2[0][1]+=a0*b1; cc2[0][2]+=a0*b2; cc2[0][3]+=a0*b3;
      cc2[1][0]+=a1*b0; cc2[1][1]+=a1*b1; cc2[1][2]+=a1*b2; cc2[1][3]+=a1*b3;
      cc2[2][0]+=a2*b0; cc2[2][1]+=a2*b1; cc2[2][2]+=a2*b2; cc2[2][3]+=a2*b3;
      cc2[3][0]+=a3*b0; cc2[3][1]+=a3*b1; cc2[3][2]+=a3*b2; cc2[3][3]+=a3*b3;
    }
  }
  __syncthreads();
  #pragma unroll
  for (int u = 0; u < 4; ++u)
    #pragma unroll
    for (int v = 0; v < 4; ++v)
      Ub[tr + u][tc + v] = G[(rI + tr + u) * 512 + cP + tc + v] - cc2[u][v];
  __syncthreads();
  float xx[4][4] = {{0.f}};
  #pragma unroll 4
  for (int k = 0; k < 64; ++k) {
    float a0 = Ub[tr][k], a1 = Ub[tr+1][k], a2 = Ub[tr+2][k], a3 = Ub[tr+3][k];
    float b0 = Inv[tc][k], b1 = Inv[tc+1][k], b2 = Inv[tc+2][k], b3 = Inv[tc+3][k];
    xx[0][0]+=a0*b0; xx[0][1]+=a0*b1; xx[0][2]+=a0*b2; xx[0][3]+=a0*b3;
    xx[1][0]+=a1*b0; xx[1][1]+=a1*b1; xx[1][2]+=a1*b2; xx[1][3]+=a1*b3;
    xx[2][0]+=a2*b0; xx[2][1]+=a2*b1; xx[2][2]+=a2*b2; xx[2][3]+=a2*b3;
    xx[3][0]+=a3*b0; xx[3][1]+=a3*b1; xx[3][2]+=a3*b2; xx[3][3]+=a3*b3;
  }
  #pragma unroll
  for (int u = 0; u < 4; ++u)
    #pragma unroll
    for (int v = 0; v < 4; ++v)
      G[(rI + tr + u) * 512 + cP + tc + v] = xx[u][v];
}

// ---------------------------------------------------------------------------
// Kernel 4: blocked back-substitution -> PLAIN Wt (bf16, n-major), grid 8x256
// ---------------------------------------------------------------------------
__global__ __launch_bounds__(256) void tri_assemble(
    const float* __restrict__ G, const float* __restrict__ Dinv,
    unsigned short* __restrict__ Wt) {
  __shared__ float Bsh[448 * 64];   // rows for p>q, 112 KB
  __shared__ float T[64 * 64];      // 16 KB
  const int q = blockIdx.x, t = threadIdx.x;
  const int or_ = (t >> 4) * 4, oc = (t & 15) * 4;

  for (int p = q + 1; p < 8; ++p) {
    float cc[4][4] = {{0.f}};
    for (int r = q; r < p; ++r) {
      const float* Lbase = G + (long)(64 * p) * 512 + 64 * r;
      #pragma unroll 4
      for (int k = 0; k < 64; ++k) {
        float a0 = Lbase[(or_ + 0) * 512 + k];
        float a1 = Lbase[(or_ + 1) * 512 + k];
        float a2 = Lbase[(or_ + 2) * 512 + k];
        float a3 = Lbase[(or_ + 3) * 512 + k];
        float b0, b1, b2, b3;
        if (r == q) {
          const float* Bq = Dinv + q * 4096 + k * 64 + oc;
          b0 = Bq[0]; b1 = Bq[1]; b2 = Bq[2]; b3 = Bq[3];
        } else {
          const float* Br = Bsh + ((r - q - 1) * 64 + k) * 64 + oc;
          b0 = Br[0]; b1 = Br[1]; b2 = Br[2]; b3 = Br[3];
        }
        cc[0][0] += a0*b0; cc[0][1] += a0*b1; cc[0][2] += a0*b2; cc[0][3] += a0*b3;
        cc[1][0] += a1*b0; cc[1][1] += a1*b1; cc[1][2] += a1*b2; cc[1][3] += a1*b3;
        cc[2][0] += a2*b0; cc[2][1] += a2*b1; cc[2][2] += a2*b2; cc[2][3] += a2*b3;
        cc[3][0] += a3*b0; cc[3][1] += a3*b1; cc[3][2] += a3*b2; cc[3][3] += a3*b3;
      }
    }
    #pragma unroll
    for (int u = 0; u < 4; ++u)
      #pragma unroll
      for (int v = 0; v < 4; ++v)
        T[(or_ + u) * 64 + oc + v] = cc[u][v];
    __syncthreads();

    float c2[4][4] = {{0.f}};
    const float* Dp = Dinv + p * 4096;
    #pragma unroll 4
    for (int k = 0; k < 64; ++k) {
      float a0 = Dp[(or_ + 0) * 64 + k];
      float a1 = Dp[(or_ + 1) * 64 + k];
      float a2 = Dp[(or_ + 2) * 64 + k];
      float a3 = Dp[(or_ + 3) * 64 + k];
      const float* Tk = T + k * 64 + oc;
      float b0 = Tk[0], b1 = Tk[1], b2 = Tk[2], b3 = Tk[3];
      c2[0][0] += a0*b0; c2[0][1] += a0*b1; c2[0][2] += a0*b2; c2[0][3] += a0*b3;
      c2[1][0] += a1*b0; c2[1][1] += a1*b1; c2[1][2] += a1*b2; c2[1][3] += a1*b3;
      c2[2][0] += a2*b0; c2[2][1] += a2*b1; c2[2][2] += a2*b2; c2[2][3] += a2*b3;
      c2[3][0] += a3*b0; c2[3][1] += a3*b1; c2[3][2] += a3*b2; c2[3][3] += a3*b3;
    }
    #pragma unroll
    for (int u = 0; u < 4; ++u)
      #pragma unroll
      for (int v = 0; v < 4; ++v)
        Bsh[((p - q - 1) * 64 + or_ + u) * 64 + oc + v] = -c2[u][v];
    __syncthreads();
  }

  const int nr = (8 - q) * 64;
  for (int idx = t; idx < nr * 64; idx += 256) {
    int i = idx >> 6, kk = idx & 63;
    float v = (i < 64) ? Dinv[q * 4096 + i * 64 + kk]
                       : Bsh[(i - 64) * 64 + kk];
    int n = 64 * q + i;
    Wt[(long)n * 512 + 64 * q + kk] = f2bf(SQRTD * v);
  }
  for (int idx = t; idx < 64 * q * 64; idx += 256) {   // zeros above diagonal
    int n = idx >> 6, kk = idx & 63;
    Wt[(long)n * 512 + 64 * q + kk] = 0;
  }
}

// ---------------------------------------------------------------------------
// Kernel 5 (fast path): Y = Xbf @ W.  512 thr, dbuf global_load_lds for A+B,
// counted vmcnt(4) + raw s_barriers (next-tile loads stay in flight).
// XCD-bijective 1-D grid.
// ---------------------------------------------------------------------------
__global__ __launch_bounds__(512, 4) void ymm5(
    const unsigned short* __restrict__ Xbf,
    const unsigned short* __restrict__ Wt, float* __restrict__ Y) {
  __shared__ unsigned short As[2][128 * 64];
  __shared__ unsigned short Bs[2][128 * 64];
  const int t = threadIdx.x, lane = t & 63, w = t >> 6;
  const int id = blockIdx.x;
  const int xcd = id & 7, j = id >> 3;
  const long m0 = (long)((j >> 2) * 8 + xcd) * 128;
  const int n0 = (j & 3) * 128;
  const int wm = (w >> 1) * 32, wn = (w & 1) * 64;
  f32x4 acc[2][4];
  const f32x4 zf = {0.f, 0.f, 0.f, 0.f};
  #pragma unroll
  for (int a = 0; a < 2; ++a)
    #pragma unroll
    for (int bq = 0; bq < 4; ++bq) acc[a][bq] = zf;

  auto stage = [&](int buf, int k0) {   // exactly 4 loads per thread
    #pragma unroll
    for (int h = 0; h < 2; ++h) {
      int seg = t + h * 512;
      int row = seg >> 3, sl = seg & 7;
      const unsigned short* sA =
          Xbf + (m0 + row) * 512 + k0 + swz(row, sl) * 8;
      const unsigned short* sB =
          Wt + (long)(n0 + row) * 512 + k0 + swz(row, sl) * 8;
      GLOAD16(sA, &As[buf][seg * 8]);
      GLOAD16(sB, &Bs[buf][seg * 8]);
    }
  };
  auto compute = [&](int buf) {
    #pragma unroll
    for (int kk = 0; kk < 2; ++kk) {
      bf16x8 af[2], bfr[4];
      #pragma unroll
      for (int fm = 0; fm < 2; ++fm) {
        int row = wm + fm * 16 + (lane & 15);
        af[fm] = *(const bf16x8*)((const char*)As[buf] + row * 128 +
                                  swz(row, kk * 4 + (lane >> 4)) * 16);
      }
      #pragma unroll
      for (int fn = 0; fn < 4; ++fn) {
        int row = wn + fn * 16 + (lane & 15);
        bfr[fn] = *(const bf16x8*)((const char*)Bs[buf] + row * 128 +
                                   swz(row, kk * 4 + (lane >> 4)) * 16);
      }
      #pragma unroll
      for (int fm = 0; fm < 2; ++fm)
        #pragma unroll
        for (int fn = 0; fn < 4; ++fn)
          acc[fm][fn] = __builtin_amdgcn_mfma_f32_16x16x32_bf16(
              bfr[fn], af[fm], acc[fm][fn], 0, 0, 0);   // swapped
    }
  };

  stage(0, 0);
  asm volatile("s_waitcnt vmcnt(0)" ::: "memory");
  __builtin_amdgcn_s_barrier();
  int cur = 0;
  #pragma unroll 1
  for (int kt = 0; kt < 7; ++kt) {
    stage(cur ^ 1, (kt + 1) * 64);      // 4 new loads in flight
    asm volatile("s_waitcnt vmcnt(4)" ::: "memory");   // cur tile done
    __builtin_amdgcn_sched_barrier(0);
    __builtin_amdgcn_s_barrier();       // all waves' cur writes visible
    compute(cur);
    __builtin_amdgcn_s_barrier();       // protect cur buf before re-stage
    cur ^= 1;
  }
  asm volatile("s_waitcnt vmcnt(0)" ::: "memory");
  __builtin_amdgcn_sched_barrier(0);
  __builtin_amdgcn_s_barrier();
  compute(cur);

  #pragma unroll
  for (int fm = 0; fm < 2; ++fm)
    #pragma unroll
    for (int fn = 0; fn < 4; ++fn) {
      long row = m0 + wm + fm * 16 + (lane & 15);
      int col = n0 + wn + fn * 16 + (lane >> 4) * 4;
      *(float4*)(Y + row * 512 + col) = *(float4*)&acc[fm][fn];
    }
}

// ---------------------------------------------------------------------------
// Kernel 5b (fallback): fp32 X reg-staged ymm, plain Wt.
// ---------------------------------------------------------------------------
__global__ __launch_bounds__(256) void ymm_v1(const float* __restrict__ X,
                                              const unsigned short* __restrict__ Wt,
                                              float* __restrict__ Y) {
  __shared__ unsigned short As[128 * 64];
  __shared__ unsigned short Bs[128 * 64];
  const int t = threadIdx.x, lane = t & 63, w = t >> 6;
  const long m0 = (long)blockIdx.x * 128;
  const int n0 = blockIdx.y * 128;
  const int wm = (w >> 1) * 64, wn = (w & 1) * 64;
  f32x4 acc[4][4];
  const f32x4 zf = {0.f, 0.f, 0.f, 0.f};
  #pragma unroll
  for (int a = 0; a < 4; ++a)
    #pragma unroll
    for (int bq = 0; bq < 4; ++bq) acc[a][bq] = zf;
  const int ko = t & 7, mrow = t >> 3;

  for (int k0 = 0; k0 < 512; k0 += 64) {
    #pragma unroll
    for (int it = 0; it < 4; ++it) {
      int m = mrow + 32 * it;
      const float4* src = (const float4*)(X + (m0 + m) * 512 + k0 + ko * 8);
      float4 f0 = src[0], f1 = src[1];
      unsigned p0 = (unsigned)f2bf(f0.x) | ((unsigned)f2bf(f0.y) << 16);
      unsigned p1 = (unsigned)f2bf(f0.z) | ((unsigned)f2bf(f0.w) << 16);
      unsigned p2 = (unsigned)f2bf(f1.x) | ((unsigned)f2bf(f1.y) << 16);
      unsigned p3 = (unsigned)f2bf(f1.z) | ((unsigned)f2bf(f1.w) << 16);
      int slot = swz(m, ko);
      *(uint4*)((char*)As + m * 128 + slot * 16) = make_uint4(p0, p1, p2, p3);
    }
    #pragma unroll
    for (int it = 0; it < 4; ++it) {
      int n = mrow + 32 * it;
      uint4 raw = *(const uint4*)(Wt + (long)(n0 + n) * 512 + k0 + ko * 8);
      int slot = swz(n, ko);
      *(uint4*)((char*)Bs + n * 128 + slot * 16) = raw;
    }
    __syncthreads();
    #pragma unroll
    for (int kk = 0; kk < 2; ++kk) {
      bf16x8 af[4], bfr[4];
      #pragma unroll
      for (int fm = 0; fm < 4; ++fm) {
        int row = wm + fm * 16 + (lane & 15);
        af[fm] = *(const bf16x8*)((const char*)As + row * 128 +
                                  swz(row, kk * 4 + (lane >> 4)) * 16);
      }
      #pragma unroll
      for (int fn = 0; fn < 4; ++fn) {
        int row = wn + fn * 16 + (lane & 15);
        bfr[fn] = *(const bf16x8*)((const char*)Bs + row * 128 +
                                   swz(row, kk * 4 + (lane >> 4)) * 16);
      }
      #pragma unroll
      for (int fm = 0; fm < 4; ++fm)
        #pragma unroll
        for (int fn = 0; fn < 4; ++fn)
          acc[fm][fn] = __builtin_amdgcn_mfma_f32_16x16x32_bf16(
              af[fm], bfr[fn], acc[fm][fn], 0, 0, 0);
    }
    __syncthreads();
  }
  #pragma unroll
  for (int fm = 0; fm < 4; ++fm)
    #pragma unroll
    for (int fn = 0; fn < 4; ++fn)
      #pragma unroll
      for (int j = 0; j < 4; ++j) {
        long row = m0 + wm + fm * 16 + (lane >> 4) * 4 + j;
        int col = n0 + wn + fn * 16 + (lane & 15);
        Y[row * 512 + col] = acc[fm][fn][j];
      }
}

// ---------------------------------------------------------------------------
extern "C" void kernel_launch(void* const* d_in, const int* in_sizes, int n_in,
                              void* d_out, int out_size, void* d_ws, size_t ws_size,
                              hipStream_t stream) {
  const float* X = (const float*)d_in[0];
  float* Y = (float*)d_out;
  char* ws = (char*)d_ws;
  float* G = (float*)ws;                                     // 1 MiB fp32
  unsigned short* Wt = (unsigned short*)(ws + (1 << 20));    // 512 KiB bf16
  float* Dinv = (float*)(ws + (1 << 20) + (1 << 19));        // 128 KiB fp32

  const int NCH = 255;
  size_t part_off = (size_t)(2 << 20);
  size_t part_bytes = (size_t)NCH * 3 * 65536 * 4;           // ~200 MB
  size_t xbf_off = part_off + part_bytes;
  size_t need = xbf_off + (size_t)134217728 * 2;             // + 256 MiB

  if (ws_size >= need) {
    float* part = (float*)(ws + part_off);
    unsigned short* Xbf = (unsigned short*)(ws + xbf_off);
    gram_k1<<<NCH, 512, 0, stream>>>(X, Xbf, part, NCH);
    gram_k2<<<2 * NCH, 512, 0, stream>>>(Xbf, part, NCH);
    gram_reduce<<<768, 256, 0, stream>>>(part, G, NCH);
    for (int p = 0; p < 8; ++p)
      chol_step<<<8 - p, 256, 0, stream>>>(G, Dinv, p);
    tri_assemble<<<8, 256, 0, stream>>>(G, Dinv, Wt);
    ymm5<<<8192, 512, 0, stream>>>(Xbf, Wt, Y);
  } else {
    float* part = (float*)(ws + part_off);
    size_t fixed = part_off;
    int nchunk = 64;
    while (nchunk > 1 && fixed + (size_t)nchunk * 3 * 65536 * 4 > ws_size)
      nchunk >>= 1;
    gram_f32<<<3 * nchunk, 512, 0, stream>>>(X, part, nchunk);
    gram_reduce<<<768, 256, 0, stream>>>(part, G, nchunk);
    for (int p = 0; p < 8; ++p)
      chol_step<<<8 - p, 256, 0, stream>>>(G, Dinv, p);
    tri_assemble<<<8, 256, 0, stream>>>(G, Dinv, Wt);
    ymm_v1<<<dim3(2048, 4), 256, 0, stream>>>(X, Wt, Y);
  }
}

// Round 8
// 1429.045 us; speedup vs baseline: 1.1061x; 1.1061x over previous
//
#include <hip/hip_runtime.h>

// Orthonorm: Y = X * (sqrt(512) * inv(chol(X^T X + eps I))^T)
// X: [262144, 512] fp32.  Heavy matmuls via bf16 MFMA (fp32 accum).
// r8 = measured r6 config (1412us) with ONE change: ymm6 (n-tile 64,
// LDS 48KB -> 3 blocks/CU, 24 waves/CU vs ymm4's 16).  Everything else
// byte-identical to r6: conv, gram_bf (b64 packs, NCH 85), chol_d64/t64
// (32-reg serial parts only -- r3 post-mortem), tri_assemble plain Wt.

#define EPSJ 1e-6f
#define SQRTD 22.627416997969522f

typedef short bf16x8 __attribute__((ext_vector_type(8)));
typedef float f32x4 __attribute__((ext_vector_type(4)));

__device__ __forceinline__ unsigned short f2bf(float f) {
  unsigned u = __float_as_uint(f);
  unsigned r = u + 0x7fffu + ((u >> 16) & 1u);   // RNE
  return (unsigned short)(r >> 16);
}

// 16B-slot XOR swizzle within a 128B LDS row (8 slots). Involution in slot.
__device__ __forceinline__ int swz(int row, int slot) {
  return slot ^ ((row ^ (row >> 3)) & 7);
}

__device__ __forceinline__ float wred(float s) {
  s += __shfl_xor(s, 1);  s += __shfl_xor(s, 2);  s += __shfl_xor(s, 4);
  s += __shfl_xor(s, 8);  s += __shfl_xor(s, 16); s += __shfl_xor(s, 32);
  return s;
}

#define GLOAD16(g, l)                                                         \
  __builtin_amdgcn_global_load_lds(                                           \
      (const __attribute__((address_space(1))) void*)(g),                     \
      (__attribute__((address_space(3))) void*)(l), 16, 0, 0)

// ---------------------------------------------------------------------------
// Kernel 0 (fast path): X fp32 -> Xbf bf16.  grid 2048 x 256.
// ---------------------------------------------------------------------------
__global__ void convert_bf(const float* __restrict__ X,
                           unsigned short* __restrict__ Xbf) {
  long idx = (long)blockIdx.x * blockDim.x + threadIdx.x;
  const long stride = (long)gridDim.x * blockDim.x;
  const long nch = 134217728 / 8;
  for (long i = idx; i < nch; i += stride) {
    float4 f0 = ((const float4*)X)[i * 2];
    float4 f1 = ((const float4*)X)[i * 2 + 1];
    uint4 o;
    o.x = (unsigned)f2bf(f0.x) | ((unsigned)f2bf(f0.y) << 16);
    o.y = (unsigned)f2bf(f0.z) | ((unsigned)f2bf(f0.w) << 16);
    o.z = (unsigned)f2bf(f1.x) | ((unsigned)f2bf(f1.y) << 16);
    o.w = (unsigned)f2bf(f1.z) | ((unsigned)f2bf(f1.w) << 16);
    ((uint4*)Xbf)[i] = o;
  }
}

// ---------------------------------------------------------------------------
// Kernel 1 (fast path): Gram partials from bf16 X. grid = 3*nchunk x 512.
// pos = b%3: (0,0),(256,256),(0,256) 256x256 tiles; LDS [c][k] swizzled.
// Staging: each thread packs 4 k-rows x 8 cols -> 8 ds_write_b64 per k-step.
// MFMA operand-swapped; float4 stores.
// ---------------------------------------------------------------------------
__device__ __forceinline__ void stage_pack4(
    const unsigned short* __restrict__ src,   // row k, col c0 (rows 512 apart)
    unsigned short* dst, int c0, int kg) {
  uint4 r0 = *(const uint4*)src;
  uint4 r1 = *(const uint4*)(src + 512);
  uint4 r2 = *(const uint4*)(src + 1024);
  uint4 r3 = *(const uint4*)(src + 1536);
  unsigned a[4] = {r0.x, r0.y, r0.z, r0.w};
  unsigned b[4] = {r1.x, r1.y, r1.z, r1.w};
  unsigned c[4] = {r2.x, r2.y, r2.z, r2.w};
  unsigned d[4] = {r3.x, r3.y, r3.z, r3.w};
  const int khi = kg >> 1, koff = (kg & 1) * 8;
  #pragma unroll
  for (int s = 0; s < 8; ++s) {
    int wsel = s >> 1, sh = (s & 1) * 16;
    unsigned v0 = (a[wsel] >> sh) & 0xFFFFu;
    unsigned v1 = (b[wsel] >> sh) & 0xFFFFu;
    unsigned v2 = (c[wsel] >> sh) & 0xFFFFu;
    unsigned v3 = (d[wsel] >> sh) & 0xFFFFu;
    int cc = c0 + s;
    int sl = khi ^ ((cc ^ (cc >> 3)) & 7);
    *(uint2*)((char*)dst + cc * 128 + sl * 16 + koff) =
        make_uint2(v0 | (v1 << 16), v2 | (v3 << 16));
  }
}

__global__ __launch_bounds__(512, 2) void gram_bf(
    const unsigned short* __restrict__ Xbf, float* __restrict__ part,
    int nchunk) {
  __shared__ unsigned short As[256 * 64];
  __shared__ unsigned short Bs[256 * 64];
  const int b = blockIdx.x, pos = b % 3, chunk = b / 3;
  const int s0 = (int)((long)4096 * chunk / nchunk);
  const int s1 = (int)((long)4096 * (chunk + 1) / nchunk);
  const int ca = (pos == 1) ? 256 : 0;
  const int cb2 = (pos == 0) ? 0 : 256;
  const bool diag = (pos != 2);
  const int t = threadIdx.x, lane = t & 63, w = t >> 6;
  const int wr = w >> 2, wc = w & 3;

  f32x4 acc[8][4];
  const f32x4 zf = {0.f, 0.f, 0.f, 0.f};
  #pragma unroll
  for (int a = 0; a < 8; ++a)
    #pragma unroll
    for (int bb = 0; bb < 4; ++bb) acc[a][bb] = zf;

  const int c0 = (t & 31) * 8;   // relative col octet
  const int kg = t >> 5;         // k-group 0..15 (k = 4*kg .. 4*kg+3)

  for (int ks = s0; ks < s1; ++ks) {
    long r = (long)ks * 64 + kg * 4;
    stage_pack4(Xbf + r * 512 + ca + c0, As, c0, kg);
    if (!diag) stage_pack4(Xbf + r * 512 + cb2 + c0, Bs, c0, kg);
    __syncthreads();
    const unsigned short* Bp = diag ? As : Bs;
    #pragma unroll
    for (int kk = 0; kk < 2; ++kk) {
      bf16x8 af[8], bfr[4];
      #pragma unroll
      for (int fm = 0; fm < 8; ++fm) {
        int row = wr * 128 + fm * 16 + (lane & 15);
        int slot = swz(row, kk * 4 + (lane >> 4));
        af[fm] = *(const bf16x8*)((const char*)As + row * 128 + slot * 16);
      }
      #pragma unroll
      for (int fn = 0; fn < 4; ++fn) {
        int row = wc * 64 + fn * 16 + (lane & 15);
        int slot = swz(row, kk * 4 + (lane >> 4));
        bfr[fn] = *(const bf16x8*)((const char*)Bp + row * 128 + slot * 16);
      }
      #pragma unroll
      for (int fm = 0; fm < 8; ++fm)
        #pragma unroll
        for (int fn = 0; fn < 4; ++fn)
          acc[fm][fn] = __builtin_amdgcn_mfma_f32_16x16x32_bf16(
              bfr[fn], af[fm], acc[fm][fn], 0, 0, 0);   // swapped: reg axis = n
    }
    __syncthreads();
  }
  float* out = part + (long)b * 65536;
  #pragma unroll
  for (int fm = 0; fm < 8; ++fm)
    #pragma unroll
    for (int fn = 0; fn < 4; ++fn) {
      int mi = wr * 128 + fm * 16 + (lane & 15);
      int nj = wc * 64 + fn * 16 + (lane >> 4) * 4;
      *(float4*)(out + mi * 256 + nj) = *(float4*)&acc[fm][fn];
    }
}

// ---------------------------------------------------------------------------
// Kernel 1b (fallback): Gram partials from fp32 X.
// ---------------------------------------------------------------------------
__global__ __launch_bounds__(512, 2) void gram_f32(
    const float* __restrict__ X, float* __restrict__ part, int nchunk) {
  __shared__ unsigned short As[256 * 64];
  __shared__ unsigned short Bs[256 * 64];
  const int b = blockIdx.x;
  const int pos = b % 3;
  const int chunk = b / 3;
  const int CR = 262144 / nchunk;
  const long r0 = (long)chunk * CR;
  const int ca = (pos == 1) ? 256 : 0;
  const int cb = (pos == 0) ? 0 : 256;
  const bool diag = (pos != 2);
  const int t = threadIdx.x, lane = t & 63, w = t >> 6;
  const int wr = w >> 2, wc = w & 3;

  f32x4 acc[8][4];
  const f32x4 zf = {0.f, 0.f, 0.f, 0.f};
  #pragma unroll
  for (int a = 0; a < 8; ++a)
    #pragma unroll
    for (int bb = 0; bb < 4; ++bb) acc[a][bb] = zf;

  const int c_oct = t & 31, msub = t >> 5;

  for (int ks = 0; ks < CR; ks += 64) {
    #pragma unroll
    for (int it = 0; it < 4; ++it) {
      int m = msub + 16 * it;
      long row = r0 + ks + m;
      const float4* sa = (const float4*)(X + row * 512 + ca + c_oct * 8);
      float4 a0 = sa[0], a1 = sa[1];
      {
        float v[8] = {a0.x, a0.y, a0.z, a0.w, a1.x, a1.y, a1.z, a1.w};
        #pragma unroll
        for (int s = 0; s < 8; ++s) {
          int cc = c_oct * 8 + s;
          int off = cc * 128 + ((2 * m) ^ (((cc ^ (cc >> 3)) & 7) << 4));
          *(unsigned short*)((char*)As + off) = f2bf(v[s]);
        }
      }
      if (!diag) {
        const float4* sb = (const float4*)(X + row * 512 + cb + c_oct * 8);
        float4 b0 = sb[0], b1 = sb[1];
        float v[8] = {b0.x, b0.y, b0.z, b0.w, b1.x, b1.y, b1.z, b1.w};
        #pragma unroll
        for (int s = 0; s < 8; ++s) {
          int cc = c_oct * 8 + s;
          int off = cc * 128 + ((2 * m) ^ (((cc ^ (cc >> 3)) & 7) << 4));
          *(unsigned short*)((char*)Bs + off) = f2bf(v[s]);
        }
      }
    }
    __syncthreads();
    const unsigned short* Bp = diag ? As : Bs;
    #pragma unroll
    for (int kk = 0; kk < 2; ++kk) {
      bf16x8 af[8], bfr[4];
      #pragma unroll
      for (int fm = 0; fm < 8; ++fm) {
        int row = wr * 128 + fm * 16 + (lane & 15);
        int slot = swz(row, kk * 4 + (lane >> 4));
        af[fm] = *(const bf16x8*)((const char*)As + row * 128 + slot * 16);
      }
      #pragma unroll
      for (int fn = 0; fn < 4; ++fn) {
        int row = wc * 64 + fn * 16 + (lane & 15);
        int slot = swz(row, kk * 4 + (lane >> 4));
        bfr[fn] = *(const bf16x8*)((const char*)Bp + row * 128 + slot * 16);
      }
      #pragma unroll
      for (int fm = 0; fm < 8; ++fm)
        #pragma unroll
        for (int fn = 0; fn < 4; ++fn)
          acc[fm][fn] = __builtin_amdgcn_mfma_f32_16x16x32_bf16(
              bfr[fn], af[fm], acc[fm][fn], 0, 0, 0);   // swapped
    }
    __syncthreads();
  }
  float* out = part + (long)b * 65536;
  #pragma unroll
  for (int fm = 0; fm < 8; ++fm)
    #pragma unroll
    for (int fn = 0; fn < 4; ++fn) {
      int mi = wr * 128 + fm * 16 + (lane & 15);
      int nj = wc * 64 + fn * 16 + (lane >> 4) * 4;
      *(float4*)(out + mi * 256 + nj) = *(float4*)&acc[fm][fn];
    }
}

// ---------------------------------------------------------------------------
// Kernel 2: reduce partials -> full symmetric G [512][512] fp32. grid 768x256
// ---------------------------------------------------------------------------
__global__ void gram_reduce(const float* __restrict__ part,
                            float* __restrict__ G, int nchunk) {
  int idx = blockIdx.x * 256 + threadIdx.x;   // < 196608
  int pos = idx >> 16;
  int e = idx & 65535;
  float s = 0.f;
  for (int ch = 0; ch < nchunk; ++ch)
    s += part[(long)(ch * 3 + pos) * 65536 + e];
  int i = e >> 8, j = e & 255;
  if (pos == 0) {
    G[i * 512 + j] = s;
  } else if (pos == 1) {
    G[(256 + i) * 512 + 256 + j] = s;
  } else {
    G[i * 512 + 256 + j] = s;
    G[(256 + j) * 512 + i] = s;
  }
}

// ---------------------------------------------------------------------------
// Kernel 3: left-looking diag step, NB=64.  One block, 256 threads.
// ---------------------------------------------------------------------------
__global__ __launch_bounds__(256) void chol_d64(float* __restrict__ G,
                                                float* __restrict__ Dinv,
                                                int p) {
  __shared__ float Pb[64][65];
  __shared__ float Sb[64][65];
  __shared__ float Inv[64][65];
  __shared__ float Tt[32][33];
  const int t = threadIdx.x;
  const int r0 = 64 * p;
  const int tr = (t >> 4) * 4, tc = (t & 15) * 4;

  for (int idx = t; idx < 4096; idx += 256) {
    int i = idx >> 6, j = idx & 63;
    float v = G[(long)(r0 + i) * 512 + r0 + j];
    if (i == j) v += EPSJ;
    Pb[i][j] = v;
  }
  __syncthreads();

  if (p > 0) {
    float cc[4][4] = {{0.f}};
    for (int r = 0; r < p; ++r) {
      for (int idx = t; idx < 4096; idx += 256) {
        int i = idx >> 6, j = idx & 63;
        Sb[i][j] = G[(long)(r0 + i) * 512 + 64 * r + j];
      }
      __syncthreads();
      #pragma unroll 4
      for (int k = 0; k < 64; ++k) {
        float a0 = Sb[tr][k], a1 = Sb[tr+1][k], a2 = Sb[tr+2][k], a3 = Sb[tr+3][k];
        float b0 = Sb[tc][k], b1 = Sb[tc+1][k], b2 = Sb[tc+2][k], b3 = Sb[tc+3][k];
        cc[0][0]+=a0*b0; cc[0][1]+=a0*b1; cc[0][2]+=a0*b2; cc[0][3]+=a0*b3;
        cc[1][0]+=a1*b0; cc[1][1]+=a1*b1; cc[1][2]+=a1*b2; cc[1][3]+=a1*b3;
        cc[2][0]+=a2*b0; cc[2][1]+=a2*b1; cc[2][2]+=a2*b2; cc[2][3]+=a2*b3;
        cc[3][0]+=a3*b0; cc[3][1]+=a3*b1; cc[3][2]+=a3*b2; cc[3][3]+=a3*b3;
      }
      __syncthreads();
    }
    #pragma unroll
    for (int u = 0; u < 4; ++u)
      #pragma unroll
      for (int v = 0; v < 4; ++v)
        Pb[tr + u][tc + v] -= cc[u][v];
    __syncthreads();
  }

  const int lane = t & 63, w = t >> 6;
  #pragma unroll
  for (int sp = 0; sp < 2; ++sp) {
    const int b0 = sp * 32;
    if (w == 0) {                       // 32-col register factor (proven)
      float rr[32];
      #pragma unroll
      for (int k = 0; k < 32; ++k)
        rr[k] = (lane < 32) ? Pb[b0 + lane][b0 + k] : 0.f;
      #pragma unroll
      for (int j = 0; j < 32; ++j) {
        float d = sqrtf(__shfl(rr[j], j));
        if (lane == j) rr[j] = d;
        else if (lane > j && lane < 32) rr[j] = rr[j] / d;
        float rj = rr[j];
        #pragma unroll
        for (int k = j + 1; k < 32; ++k) {
          float Lkj = __shfl(rj, k);
          if (lane > j && lane < 32) rr[k] -= rj * Lkj;
        }
      }
      #pragma unroll
      for (int k = 0; k < 32; ++k)
        if (lane < 32) Pb[b0 + lane][b0 + k] = rr[k];
    }
    __syncthreads();
    if (sp == 0) {
      if (t < 32) {                     // solve rows 32..63 vs A (proven)
        int rw = 32 + t;
        float x[32];
        #pragma unroll
        for (int j = 0; j < 32; ++j) x[j] = Pb[rw][j];
        #pragma unroll
        for (int j = 0; j < 32; ++j) {
          float xj = x[j] / Pb[j][j];
          x[j] = xj;
          #pragma unroll
          for (int k2 = j + 1; k2 < 32; ++k2) x[k2] -= xj * Pb[k2][j];
        }
        #pragma unroll
        for (int j = 0; j < 32; ++j) Pb[rw][j] = x[j];
      }
      __syncthreads();
      {                                 // trailing 32x32 -= S S^T
        int i = 32 + (t >> 3), kb = 32 + (t & 7) * 4;
        float sv[4];
        #pragma unroll
        for (int e = 0; e < 4; ++e) sv[e] = Pb[i][kb + e];
        #pragma unroll 4
        for (int j = 0; j < 32; ++j) {
          float aij = Pb[i][j];
          #pragma unroll
          for (int e = 0; e < 4; ++e) sv[e] -= aij * Pb[kb + e][j];
        }
        #pragma unroll
        for (int e = 0; e < 4; ++e) Pb[i][kb + e] = sv[e];
      }
      __syncthreads();
    }
  }

  // invert A (0..31) and C (32..63): 64 parallel column solves (x[32])
  if (t < 64) {
    int col = t & 31, o = (t >> 5) * 32;
    float x[32];
    #pragma unroll
    for (int i = 0; i < 32; ++i) {
      float s = (i == col) ? 1.f : 0.f;
      #pragma unroll
      for (int j = 0; j < i; ++j) s -= Pb[o + i][o + j] * x[j];
      x[i] = s / Pb[o + i][o + i];
    }
    #pragma unroll
    for (int i = 0; i < 32; ++i) Inv[o + i][o + col] = x[i];
  }
  for (int idx = t; idx < 1024; idx += 256)      // zero top-right quadrant
    Inv[idx >> 5][32 + (idx & 31)] = 0.f;
  __syncthreads();
  {                                              // T1 = B * A^{-1}
    int i = t >> 3, jb = (t & 7) * 4;
    float sv[4] = {0.f, 0.f, 0.f, 0.f};
    #pragma unroll 4
    for (int k = 0; k < 32; ++k) {
      float bik = Pb[32 + i][k];
      #pragma unroll
      for (int e = 0; e < 4; ++e) sv[e] += bik * Inv[k][jb + e];
    }
    #pragma unroll
    for (int e = 0; e < 4; ++e) Tt[i][jb + e] = sv[e];
  }
  __syncthreads();
  {                                              // BL = -C^{-1} * T1
    int i = t >> 3, jb = (t & 7) * 4;
    float sv[4] = {0.f, 0.f, 0.f, 0.f};
    #pragma unroll 4
    for (int k = 0; k < 32; ++k) {
      float cik = Inv[32 + i][32 + k];
      #pragma unroll
      for (int e = 0; e < 4; ++e) sv[e] += cik * Tt[k][jb + e];
    }
    #pragma unroll
    for (int e = 0; e < 4; ++e) Inv[32 + i][jb + e] = -sv[e];
  }
  __syncthreads();
  for (int idx = t; idx < 4096; idx += 256) {
    int i = idx >> 6, j = idx & 63;
    G[(long)(r0 + i) * 512 + r0 + j] = Pb[i][j];
    Dinv[p * 4096 + idx] = Inv[i][j];
  }
}

// ---------------------------------------------------------------------------
// Kernel 4: left-looking panel trsm-as-GEMM.  grid (7-p) x 256.
// ---------------------------------------------------------------------------
__global__ __launch_bounds__(256) void chol_t64(float* __restrict__ G,
                                                const float* __restrict__ Dinv,
                                                int p) {
  __shared__ float SbI[64][65];
  __shared__ float SbP[64][65];
  __shared__ float Ub[64][65];
  __shared__ float Db[64][65];
  const int t = threadIdx.x;
  const long rI = 64 * (p + 1 + blockIdx.x), cP = 64 * p;
  const int tr = (t >> 4) * 4, tc = (t & 15) * 4;

  for (int idx = t; idx < 4096; idx += 256)
    Db[idx >> 6][idx & 63] = Dinv[p * 4096 + idx];

  float cc[4][4] = {{0.f}};
  for (int r = 0; r < p; ++r) {
    __syncthreads();
    for (int idx = t; idx < 4096; idx += 256) {
      int i = idx >> 6, j = idx & 63;
      SbI[i][j] = G[(rI + i) * 512 + 64 * r + j];
      SbP[i][j] = G[(cP + i) * 512 + 64 * r + j];
    }
    __syncthreads();
    #pragma unroll 4
    for (int k = 0; k < 64; ++k) {
      float a0 = SbI[tr][k], a1 = SbI[tr+1][k], a2 = SbI[tr+2][k], a3 = SbI[tr+3][k];
      float b0 = SbP[tc][k], b1 = SbP[tc+1][k], b2 = SbP[tc+2][k], b3 = SbP[tc+3][k];
      cc[0][0]+=a0*b0; cc[0][1]+=a0*b1; cc[0][2]+=a0*b2; cc[0][3]+=a0*b3;
      cc[1][0]+=a1*b0; cc[1][1]+=a1*b1; cc[1][2]+=a1*b2; cc[1][3]+=a1*b3;
      cc[2][0]+=a2*b0; cc[2][1]+=a2*b1; cc[2][2]+=a2*b2; cc[2][3]+=a2*b3;
      cc[3][0]+=a3*b0; cc[3][1]+=a3*b1; cc[3][2]+=a3*b2; cc[3][3]+=a3*b3;
    }
  }
  __syncthreads();
  #pragma unroll
  for (int u = 0; u < 4; ++u)
    #pragma unroll
    for (int v = 0; v < 4; ++v)
      Ub[tr + u][tc + v] =
          G[(rI + tr + u) * 512 + cP + tc + v] - cc[u][v];
  __syncthreads();
  float xx[4][4] = {{0.f}};
  #pragma unroll 4
  for (int k = 0; k < 64; ++k) {
    float a0 = Ub[tr][k], a1 = Ub[tr+1][k], a2 = Ub[tr+2][k], a3 = Ub[tr+3][k];
    float b0 = Db[tc][k], b1 = Db[tc+1][k], b2 = Db[tc+2][k], b3 = Db[tc+3][k];
    xx[0][0]+=a0*b0; xx[0][1]+=a0*b1; xx[0][2]+=a0*b2; xx[0][3]+=a0*b3;
    xx[1][0]+=a1*b0; xx[1][1]+=a1*b1; xx[1][2]+=a1*b2; xx[1][3]+=a1*b3;
    xx[2][0]+=a2*b0; xx[2][1]+=a2*b1; xx[2][2]+=a2*b2; xx[2][3]+=a2*b3;
    xx[3][0]+=a3*b0; xx[3][1]+=a3*b1; xx[3][2]+=a3*b2; xx[3][3]+=a3*b3;
  }
  #pragma unroll
  for (int u = 0; u < 4; ++u)
    #pragma unroll
    for (int v = 0; v < 4; ++v)
      G[(rI + tr + u) * 512 + cP + tc + v] = xx[u][v];
}

// ---------------------------------------------------------------------------
// Kernel 5: blocked back-substitution -> PLAIN Wt (bf16, n-major), grid 8x256
// ---------------------------------------------------------------------------
__global__ __launch_bounds__(256) void tri_assemble(
    const float* __restrict__ G, const float* __restrict__ Dinv,
    unsigned short* __restrict__ Wt) {
  __shared__ float Bsh[448 * 64];   // rows for p>q, 112 KB
  __shared__ float T[64 * 64];      // 16 KB
  const int q = blockIdx.x, t = threadIdx.x;
  const int or_ = (t >> 4) * 4, oc = (t & 15) * 4;

  for (int p = q + 1; p < 8; ++p) {
    float cc[4][4] = {{0.f}};
    for (int r = q; r < p; ++r) {
      const float* Lbase = G + (long)(64 * p) * 512 + 64 * r;
      #pragma unroll 4
      for (int k = 0; k < 64; ++k) {
        float a0 = Lbase[(or_ + 0) * 512 + k];
        float a1 = Lbase[(or_ + 1) * 512 + k];
        float a2 = Lbase[(or_ + 2) * 512 + k];
        float a3 = Lbase[(or_ + 3) * 512 + k];
        float b0, b1, b2, b3;
        if (r == q) {
          const float* Bq = Dinv + q * 4096 + k * 64 + oc;
          b0 = Bq[0]; b1 = Bq[1]; b2 = Bq[2]; b3 = Bq[3];
        } else {
          const float* Br = Bsh + ((r - q - 1) * 64 + k) * 64 + oc;
          b0 = Br[0]; b1 = Br[1]; b2 = Br[2]; b3 = Br[3];
        }
        cc[0][0] += a0*b0; cc[0][1] += a0*b1; cc[0][2] += a0*b2; cc[0][3] += a0*b3;
        cc[1][0] += a1*b0; cc[1][1] += a1*b1; cc[1][2] += a1*b2; cc[1][3] += a1*b3;
        cc[2][0] += a2*b0; cc[2][1] += a2*b1; cc[2][2] += a2*b2; cc[2][3] += a2*b3;
        cc[3][0] += a3*b0; cc[3][1] += a3*b1; cc[3][2] += a3*b2; cc[3][3] += a3*b3;
      }
    }
    #pragma unroll
    for (int u = 0; u < 4; ++u)
      #pragma unroll
      for (int v = 0; v < 4; ++v)
        T[(or_ + u) * 64 + oc + v] = cc[u][v];
    __syncthreads();

    float c2[4][4] = {{0.f}};
    const float* Dp = Dinv + p * 4096;
    #pragma unroll 4
    for (int k = 0; k < 64; ++k) {
      float a0 = Dp[(or_ + 0) * 64 + k];
      float a1 = Dp[(or_ + 1) * 64 + k];
      float a2 = Dp[(or_ + 2) * 64 + k];
      float a3 = Dp[(or_ + 3) * 64 + k];
      const float* Tk = T + k * 64 + oc;
      float b0 = Tk[0], b1 = Tk[1], b2 = Tk[2], b3 = Tk[3];
      c2[0][0] += a0*b0; c2[0][1] += a0*b1; c2[0][2] += a0*b2; c2[0][3] += a0*b3;
      c2[1][0] += a1*b0; c2[1][1] += a1*b1; c2[1][2] += a1*b2; c2[1][3] += a1*b3;
      c2[2][0] += a2*b0; c2[2][1] += a2*b1; c2[2][2] += a2*b2; c2[2][3] += a2*b3;
      c2[3][0] += a3*b0; c2[3][1] += a3*b1; c2[3][2] += a3*b2; c2[3][3] += a3*b3;
    }
    #pragma unroll
    for (int u = 0; u < 4; ++u)
      #pragma unroll
      for (int v = 0; v < 4; ++v)
        Bsh[((p - q - 1) * 64 + or_ + u) * 64 + oc + v] = -c2[u][v];
    __syncthreads();
  }

  const int nr = (8 - q) * 64;
  for (int idx = t; idx < nr * 64; idx += 256) {
    int i = idx >> 6, kk = idx & 63;
    float v = (i < 64) ? Dinv[q * 4096 + i * 64 + kk]
                       : Bsh[(i - 64) * 64 + kk];
    int n = 64 * q + i;
    Wt[(long)n * 512 + 64 * q + kk] = f2bf(SQRTD * v);
  }
  for (int idx = t; idx < 64 * q * 64; idx += 256) {   // zeros above diagonal
    int n = idx >> 6, kk = idx & 63;
    Wt[(long)n * 512 + 64 * q + kk] = 0;
  }
}

// ---------------------------------------------------------------------------
// Kernel 6 (fast path): Y = Xbf @ W.  ymm6: m-tile 128, n-tile 64, 512 thr
// (8 waves, 32x32 wave-tiles), LDS 48 KB -> 3 blocks/CU (24 waves/CU).
// A+B via global_load_lds dbuf, pre-swizzled per-lane sources (plain Wt).
// XCD-bijective grid 16384: xcd = id&7, j = id>>3, n0 = (j&7)*64,
// m-tile = (j>>3)*8 + xcd  (all 8 n-siblings of an m-tile on one XCD).
// ---------------------------------------------------------------------------
__global__ __launch_bounds__(512, 6) void ymm6(
    const unsigned short* __restrict__ Xbf,
    const unsigned short* __restrict__ Wt, float* __restrict__ Y) {
  __shared__ unsigned short As[2][128 * 64];
  __shared__ unsigned short Bs[2][64 * 64];
  const int t = threadIdx.x, lane = t & 63, w = t >> 6;
  const int id = blockIdx.x;
  const int xcd = id & 7, j = id >> 3;
  const long m0 = (long)((j >> 3) * 8 + xcd) * 128;
  const int n0 = (j & 7) * 64;
  const int wm = (w >> 1) * 32, wn = (w & 1) * 32;
  f32x4 acc[2][2];
  const f32x4 zf = {0.f, 0.f, 0.f, 0.f};
  #pragma unroll
  for (int a = 0; a < 2; ++a)
    #pragma unroll
    for (int bq = 0; bq < 2; ++bq) acc[a][bq] = zf;

  auto stage = [&](int buf, int k0) {   // 3 loads per thread
    #pragma unroll
    for (int h = 0; h < 2; ++h) {
      int seg = t + h * 512;
      int row = seg >> 3, sl = seg & 7;
      const unsigned short* sA =
          Xbf + (m0 + row) * 512 + k0 + swz(row, sl) * 8;
      GLOAD16(sA, &As[buf][seg * 8]);
    }
    {
      int row = t >> 3, sl = t & 7;
      const unsigned short* sB =
          Wt + (long)(n0 + row) * 512 + k0 + swz(row, sl) * 8;
      GLOAD16(sB, &Bs[buf][t * 8]);
    }
  };
  auto compute = [&](int buf) {
    #pragma unroll
    for (int kk = 0; kk < 2; ++kk) {
      bf16x8 af[2], bfr[2];
      #pragma unroll
      for (int fm = 0; fm < 2; ++fm) {
        int row = wm + fm * 16 + (lane & 15);
        af[fm] = *(const bf16x8*)((const char*)As[buf] + row * 128 +
                                  swz(row, kk * 4 + (lane >> 4)) * 16);
      }
      #pragma unroll
      for (int fn = 0; fn < 2; ++fn) {
        int row = wn + fn * 16 + (lane & 15);
        bfr[fn] = *(const bf16x8*)((const char*)Bs[buf] + row * 128 +
                                   swz(row, kk * 4 + (lane >> 4)) * 16);
      }
      #pragma unroll
      for (int fm = 0; fm < 2; ++fm)
        #pragma unroll
        for (int fn = 0; fn < 2; ++fn)
          acc[fm][fn] = __builtin_amdgcn_mfma_f32_16x16x32_bf16(
              bfr[fn], af[fm], acc[fm][fn], 0, 0, 0);   // swapped: reg axis = n
    }
  };

  stage(0, 0);
  __syncthreads();
  int cur = 0;
  #pragma unroll 1
  for (int kt = 0; kt < 7; ++kt) {
    stage(cur ^ 1, (kt + 1) * 64);
    compute(cur);
    __syncthreads();
    cur ^= 1;
  }
  compute(cur);

  #pragma unroll
  for (int fm = 0; fm < 2; ++fm)
    #pragma unroll
    for (int fn = 0; fn < 2; ++fn) {
      long row = m0 + wm + fm * 16 + (lane & 15);
      int col = n0 + wn + fn * 16 + (lane >> 4) * 4;
      *(float4*)(Y + row * 512 + col) = *(float4*)&acc[fm][fn];
    }
}

// ---------------------------------------------------------------------------
// Kernel 6b (fallback): fp32 X reg-staged ymm, plain Wt.
// ---------------------------------------------------------------------------
__global__ __launch_bounds__(256) void ymm_v1(const float* __restrict__ X,
                                              const unsigned short* __restrict__ Wt,
                                              float* __restrict__ Y) {
  __shared__ unsigned short As[128 * 64];
  __shared__ unsigned short Bs[128 * 64];
  const int t = threadIdx.x, lane = t & 63, w = t >> 6;
  const long m0 = (long)blockIdx.x * 128;
  const int n0 = blockIdx.y * 128;
  const int wm = (w >> 1) * 64, wn = (w & 1) * 64;
  f32x4 acc[4][4];
  const f32x4 zf = {0.f, 0.f, 0.f, 0.f};
  #pragma unroll
  for (int a = 0; a < 4; ++a)
    #pragma unroll
    for (int bq = 0; bq < 4; ++bq) acc[a][bq] = zf;
  const int ko = t & 7, mrow = t >> 3;

  for (int k0 = 0; k0 < 512; k0 += 64) {
    #pragma unroll
    for (int it = 0; it < 4; ++it) {
      int m = mrow + 32 * it;
      const float4* src = (const float4*)(X + (m0 + m) * 512 + k0 + ko * 8);
      float4 f0 = src[0], f1 = src[1];
      unsigned p0 = (unsigned)f2bf(f0.x) | ((unsigned)f2bf(f0.y) << 16);
      unsigned p1 = (unsigned)f2bf(f0.z) | ((unsigned)f2bf(f0.w) << 16);
      unsigned p2 = (unsigned)f2bf(f1.x) | ((unsigned)f2bf(f1.y) << 16);
      unsigned p3 = (unsigned)f2bf(f1.z) | ((unsigned)f2bf(f1.w) << 16);
      int slot = swz(m, ko);
      *(uint4*)((char*)As + m * 128 + slot * 16) = make_uint4(p0, p1, p2, p3);
    }
    #pragma unroll
    for (int it = 0; it < 4; ++it) {
      int n = mrow + 32 * it;
      uint4 raw = *(const uint4*)(Wt + (long)(n0 + n) * 512 + k0 + ko * 8);
      int slot = swz(n, ko);
      *(uint4*)((char*)Bs + n * 128 + slot * 16) = raw;
    }
    __syncthreads();
    #pragma unroll
    for (int kk = 0; kk < 2; ++kk) {
      bf16x8 af[4], bfr[4];
      #pragma unroll
      for (int fm = 0; fm < 4; ++fm) {
        int row = wm + fm * 16 + (lane & 15);
        af[fm] = *(const bf16x8*)((const char*)As + row * 128 +
                                  swz(row, kk * 4 + (lane >> 4)) * 16);
      }
      #pragma unroll
      for (int fn = 0; fn < 4; ++fn) {
        int row = wn + fn * 16 + (lane & 15);
        bfr[fn] = *(const bf16x8*)((const char*)Bs + row * 128 +
                                   swz(row, kk * 4 + (lane >> 4)) * 16);
      }
      #pragma unroll
      for (int fm = 0; fm < 4; ++fm)
        #pragma unroll
        for (int fn = 0; fn < 4; ++fn)
          acc[fm][fn] = __builtin_amdgcn_mfma_f32_16x16x32_bf16(
              af[fm], bfr[fn], acc[fm][fn], 0, 0, 0);
    }
    __syncthreads();
  }
  #pragma unroll
  for (int fm = 0; fm < 4; ++fm)
    #pragma unroll
    for (int fn = 0; fn < 4; ++fn)
      #pragma unroll
      for (int j = 0; j < 4; ++j) {
        long row = m0 + wm + fm * 16 + (lane >> 4) * 4 + j;
        int col = n0 + wn + fn * 16 + (lane & 15);
        Y[row * 512 + col] = acc[fm][fn][j];
      }
}

// ---------------------------------------------------------------------------
static void chol_chain(float* G, float* Dinv, hipStream_t stream) {
  for (int p = 0; p < 8; ++p) {
    chol_d64<<<1, 256, 0, stream>>>(G, Dinv, p);
    if (p < 7) chol_t64<<<7 - p, 256, 0, stream>>>(G, Dinv, p);
  }
}

extern "C" void kernel_launch(void* const* d_in, const int* in_sizes, int n_in,
                              void* d_out, int out_size, void* d_ws, size_t ws_size,
                              hipStream_t stream) {
  const float* X = (const float*)d_in[0];
  float* Y = (float*)d_out;
  char* ws = (char*)d_ws;
  float* G = (float*)ws;                                     // 1 MiB fp32
  unsigned short* Wt = (unsigned short*)(ws + (1 << 20));    // 512 KiB bf16
  float* Dinv = (float*)(ws + (1 << 20) + (1 << 19));        // 128 KiB fp32

  const int NCH_FAST = 85;
  size_t part_off = (size_t)(2 << 20);
  size_t part_bytes = (size_t)NCH_FAST * 3 * 65536 * 4;      // 66.8 MB
  size_t xbf_off = part_off + part_bytes;
  size_t need = xbf_off + (size_t)134217728 * 2;             // + 256 MiB

  if (ws_size >= need) {
    float* part = (float*)(ws + part_off);
    unsigned short* Xbf = (unsigned short*)(ws + xbf_off);
    convert_bf<<<2048, 256, 0, stream>>>(X, Xbf);
    gram_bf<<<3 * NCH_FAST, 512, 0, stream>>>(Xbf, part, NCH_FAST);
    gram_reduce<<<768, 256, 0, stream>>>(part, G, NCH_FAST);
    chol_chain(G, Dinv, stream);
    tri_assemble<<<8, 256, 0, stream>>>(G, Dinv, Wt);
    ymm6<<<16384, 512, 0, stream>>>(Xbf, Wt, Y);
  } else {
    float* part = (float*)(ws + part_off);
    size_t fixed = part_off;
    int nchunk = 64;
    while (nchunk > 1 && fixed + (size_t)nchunk * 3 * 65536 * 4 > ws_size)
      nchunk >>= 1;
    gram_f32<<<3 * nchunk, 512, 0, stream>>>(X, part, nchunk);
    gram_reduce<<<768, 256, 0, stream>>>(part, G, nchunk);
    chol_chain(G, Dinv, stream);
    tri_assemble<<<8, 256, 0, stream>>>(G, Dinv, Wt);
    ymm_v1<<<dim3(2048, 4), 256, 0, stream>>>(X, Wt, Y);
  }
}

// Round 9
// 1409.928 us; speedup vs baseline: 1.1211x; 1.0136x over previous
//
#include <hip/hip_runtime.h>

// Orthonorm: Y = X * (sqrt(512) * inv(chol(X^T X + eps I))^T)
// X: [262144, 512] fp32.  Heavy matmuls via bf16 MFMA (fp32 accum).
// r9 = measured r6 config (1412us) with ONE change: ymm7 = ymm4 geometry +
// counted s_waitcnt vmcnt(4) loop (T4).  __syncthreads drains vmcnt(0) and
// kills the prefetch (r6/r8 post-mortem); ymm7 keeps the next-tile
// global_load_lds in flight across the barrier.  NO sched_barrier(0) --
// r7's ymm5 pinned the scheduler every iteration (m141: ~-40%).
// lgkmcnt(0) before the 2nd barrier protects the buffer being re-staged.
// Everything else byte-identical to r6.

#define EPSJ 1e-6f
#define SQRTD 22.627416997969522f

typedef short bf16x8 __attribute__((ext_vector_type(8)));
typedef float f32x4 __attribute__((ext_vector_type(4)));

__device__ __forceinline__ unsigned short f2bf(float f) {
  unsigned u = __float_as_uint(f);
  unsigned r = u + 0x7fffu + ((u >> 16) & 1u);   // RNE
  return (unsigned short)(r >> 16);
}

// 16B-slot XOR swizzle within a 128B LDS row (8 slots). Involution in slot.
__device__ __forceinline__ int swz(int row, int slot) {
  return slot ^ ((row ^ (row >> 3)) & 7);
}

__device__ __forceinline__ float wred(float s) {
  s += __shfl_xor(s, 1);  s += __shfl_xor(s, 2);  s += __shfl_xor(s, 4);
  s += __shfl_xor(s, 8);  s += __shfl_xor(s, 16); s += __shfl_xor(s, 32);
  return s;
}

#define GLOAD16(g, l)                                                         \
  __builtin_amdgcn_global_load_lds(                                           \
      (const __attribute__((address_space(1))) void*)(g),                     \
      (__attribute__((address_space(3))) void*)(l), 16, 0, 0)

// ---------------------------------------------------------------------------
// Kernel 0 (fast path): X fp32 -> Xbf bf16.  grid 2048 x 256.
// ---------------------------------------------------------------------------
__global__ void convert_bf(const float* __restrict__ X,
                           unsigned short* __restrict__ Xbf) {
  long idx = (long)blockIdx.x * blockDim.x + threadIdx.x;
  const long stride = (long)gridDim.x * blockDim.x;
  const long nch = 134217728 / 8;
  for (long i = idx; i < nch; i += stride) {
    float4 f0 = ((const float4*)X)[i * 2];
    float4 f1 = ((const float4*)X)[i * 2 + 1];
    uint4 o;
    o.x = (unsigned)f2bf(f0.x) | ((unsigned)f2bf(f0.y) << 16);
    o.y = (unsigned)f2bf(f0.z) | ((unsigned)f2bf(f0.w) << 16);
    o.z = (unsigned)f2bf(f1.x) | ((unsigned)f2bf(f1.y) << 16);
    o.w = (unsigned)f2bf(f1.z) | ((unsigned)f2bf(f1.w) << 16);
    ((uint4*)Xbf)[i] = o;
  }
}

// ---------------------------------------------------------------------------
// Kernel 1 (fast path): Gram partials from bf16 X. grid = 3*nchunk x 512.
// pos = b%3: (0,0),(256,256),(0,256) 256x256 tiles; LDS [c][k] swizzled.
// ---------------------------------------------------------------------------
__device__ __forceinline__ void stage_pack4(
    const unsigned short* __restrict__ src,   // row k, col c0 (rows 512 apart)
    unsigned short* dst, int c0, int kg) {
  uint4 r0 = *(const uint4*)src;
  uint4 r1 = *(const uint4*)(src + 512);
  uint4 r2 = *(const uint4*)(src + 1024);
  uint4 r3 = *(const uint4*)(src + 1536);
  unsigned a[4] = {r0.x, r0.y, r0.z, r0.w};
  unsigned b[4] = {r1.x, r1.y, r1.z, r1.w};
  unsigned c[4] = {r2.x, r2.y, r2.z, r2.w};
  unsigned d[4] = {r3.x, r3.y, r3.z, r3.w};
  const int khi = kg >> 1, koff = (kg & 1) * 8;
  #pragma unroll
  for (int s = 0; s < 8; ++s) {
    int wsel = s >> 1, sh = (s & 1) * 16;
    unsigned v0 = (a[wsel] >> sh) & 0xFFFFu;
    unsigned v1 = (b[wsel] >> sh) & 0xFFFFu;
    unsigned v2 = (c[wsel] >> sh) & 0xFFFFu;
    unsigned v3 = (d[wsel] >> sh) & 0xFFFFu;
    int cc = c0 + s;
    int sl = khi ^ ((cc ^ (cc >> 3)) & 7);
    *(uint2*)((char*)dst + cc * 128 + sl * 16 + koff) =
        make_uint2(v0 | (v1 << 16), v2 | (v3 << 16));
  }
}

__global__ __launch_bounds__(512, 2) void gram_bf(
    const unsigned short* __restrict__ Xbf, float* __restrict__ part,
    int nchunk) {
  __shared__ unsigned short As[256 * 64];
  __shared__ unsigned short Bs[256 * 64];
  const int b = blockIdx.x, pos = b % 3, chunk = b / 3;
  const int s0 = (int)((long)4096 * chunk / nchunk);
  const int s1 = (int)((long)4096 * (chunk + 1) / nchunk);
  const int ca = (pos == 1) ? 256 : 0;
  const int cb2 = (pos == 0) ? 0 : 256;
  const bool diag = (pos != 2);
  const int t = threadIdx.x, lane = t & 63, w = t >> 6;
  const int wr = w >> 2, wc = w & 3;

  f32x4 acc[8][4];
  const f32x4 zf = {0.f, 0.f, 0.f, 0.f};
  #pragma unroll
  for (int a = 0; a < 8; ++a)
    #pragma unroll
    for (int bb = 0; bb < 4; ++bb) acc[a][bb] = zf;

  const int c0 = (t & 31) * 8;   // relative col octet
  const int kg = t >> 5;         // k-group 0..15 (k = 4*kg .. 4*kg+3)

  for (int ks = s0; ks < s1; ++ks) {
    long r = (long)ks * 64 + kg * 4;
    stage_pack4(Xbf + r * 512 + ca + c0, As, c0, kg);
    if (!diag) stage_pack4(Xbf + r * 512 + cb2 + c0, Bs, c0, kg);
    __syncthreads();
    const unsigned short* Bp = diag ? As : Bs;
    #pragma unroll
    for (int kk = 0; kk < 2; ++kk) {
      bf16x8 af[8], bfr[4];
      #pragma unroll
      for (int fm = 0; fm < 8; ++fm) {
        int row = wr * 128 + fm * 16 + (lane & 15);
        int slot = swz(row, kk * 4 + (lane >> 4));
        af[fm] = *(const bf16x8*)((const char*)As + row * 128 + slot * 16);
      }
      #pragma unroll
      for (int fn = 0; fn < 4; ++fn) {
        int row = wc * 64 + fn * 16 + (lane & 15);
        int slot = swz(row, kk * 4 + (lane >> 4));
        bfr[fn] = *(const bf16x8*)((const char*)Bp + row * 128 + slot * 16);
      }
      #pragma unroll
      for (int fm = 0; fm < 8; ++fm)
        #pragma unroll
        for (int fn = 0; fn < 4; ++fn)
          acc[fm][fn] = __builtin_amdgcn_mfma_f32_16x16x32_bf16(
              bfr[fn], af[fm], acc[fm][fn], 0, 0, 0);   // swapped: reg axis = n
    }
    __syncthreads();
  }
  float* out = part + (long)b * 65536;
  #pragma unroll
  for (int fm = 0; fm < 8; ++fm)
    #pragma unroll
    for (int fn = 0; fn < 4; ++fn) {
      int mi = wr * 128 + fm * 16 + (lane & 15);
      int nj = wc * 64 + fn * 16 + (lane >> 4) * 4;
      *(float4*)(out + mi * 256 + nj) = *(float4*)&acc[fm][fn];
    }
}

// ---------------------------------------------------------------------------
// Kernel 1b (fallback): Gram partials from fp32 X.
// ---------------------------------------------------------------------------
__global__ __launch_bounds__(512, 2) void gram_f32(
    const float* __restrict__ X, float* __restrict__ part, int nchunk) {
  __shared__ unsigned short As[256 * 64];
  __shared__ unsigned short Bs[256 * 64];
  const int b = blockIdx.x;
  const int pos = b % 3;
  const int chunk = b / 3;
  const int CR = 262144 / nchunk;
  const long r0 = (long)chunk * CR;
  const int ca = (pos == 1) ? 256 : 0;
  const int cb = (pos == 0) ? 0 : 256;
  const bool diag = (pos != 2);
  const int t = threadIdx.x, lane = t & 63, w = t >> 6;
  const int wr = w >> 2, wc = w & 3;

  f32x4 acc[8][4];
  const f32x4 zf = {0.f, 0.f, 0.f, 0.f};
  #pragma unroll
  for (int a = 0; a < 8; ++a)
    #pragma unroll
    for (int bb = 0; bb < 4; ++bb) acc[a][bb] = zf;

  const int c_oct = t & 31, msub = t >> 5;

  for (int ks = 0; ks < CR; ks += 64) {
    #pragma unroll
    for (int it = 0; it < 4; ++it) {
      int m = msub + 16 * it;
      long row = r0 + ks + m;
      const float4* sa = (const float4*)(X + row * 512 + ca + c_oct * 8);
      float4 a0 = sa[0], a1 = sa[1];
      {
        float v[8] = {a0.x, a0.y, a0.z, a0.w, a1.x, a1.y, a1.z, a1.w};
        #pragma unroll
        for (int s = 0; s < 8; ++s) {
          int cc = c_oct * 8 + s;
          int off = cc * 128 + ((2 * m) ^ (((cc ^ (cc >> 3)) & 7) << 4));
          *(unsigned short*)((char*)As + off) = f2bf(v[s]);
        }
      }
      if (!diag) {
        const float4* sb = (const float4*)(X + row * 512 + cb + c_oct * 8);
        float4 b0 = sb[0], b1 = sb[1];
        float v[8] = {b0.x, b0.y, b0.z, b0.w, b1.x, b1.y, b1.z, b1.w};
        #pragma unroll
        for (int s = 0; s < 8; ++s) {
          int cc = c_oct * 8 + s;
          int off = cc * 128 + ((2 * m) ^ (((cc ^ (cc >> 3)) & 7) << 4));
          *(unsigned short*)((char*)Bs + off) = f2bf(v[s]);
        }
      }
    }
    __syncthreads();
    const unsigned short* Bp = diag ? As : Bs;
    #pragma unroll
    for (int kk = 0; kk < 2; ++kk) {
      bf16x8 af[8], bfr[4];
      #pragma unroll
      for (int fm = 0; fm < 8; ++fm) {
        int row = wr * 128 + fm * 16 + (lane & 15);
        int slot = swz(row, kk * 4 + (lane >> 4));
        af[fm] = *(const bf16x8*)((const char*)As + row * 128 + slot * 16);
      }
      #pragma unroll
      for (int fn = 0; fn < 4; ++fn) {
        int row = wc * 64 + fn * 16 + (lane & 15);
        int slot = swz(row, kk * 4 + (lane >> 4));
        bfr[fn] = *(const bf16x8*)((const char*)Bp + row * 128 + slot * 16);
      }
      #pragma unroll
      for (int fm = 0; fm < 8; ++fm)
        #pragma unroll
        for (int fn = 0; fn < 4; ++fn)
          acc[fm][fn] = __builtin_amdgcn_mfma_f32_16x16x32_bf16(
              bfr[fn], af[fm], acc[fm][fn], 0, 0, 0);   // swapped
    }
    __syncthreads();
  }
  float* out = part + (long)b * 65536;
  #pragma unroll
  for (int fm = 0; fm < 8; ++fm)
    #pragma unroll
    for (int fn = 0; fn < 4; ++fn) {
      int mi = wr * 128 + fm * 16 + (lane & 15);
      int nj = wc * 64 + fn * 16 + (lane >> 4) * 4;
      *(float4*)(out + mi * 256 + nj) = *(float4*)&acc[fm][fn];
    }
}

// ---------------------------------------------------------------------------
// Kernel 2: reduce partials -> full symmetric G [512][512] fp32. grid 768x256
// ---------------------------------------------------------------------------
__global__ void gram_reduce(const float* __restrict__ part,
                            float* __restrict__ G, int nchunk) {
  int idx = blockIdx.x * 256 + threadIdx.x;   // < 196608
  int pos = idx >> 16;
  int e = idx & 65535;
  float s = 0.f;
  for (int ch = 0; ch < nchunk; ++ch)
    s += part[(long)(ch * 3 + pos) * 65536 + e];
  int i = e >> 8, j = e & 255;
  if (pos == 0) {
    G[i * 512 + j] = s;
  } else if (pos == 1) {
    G[(256 + i) * 512 + 256 + j] = s;
  } else {
    G[i * 512 + 256 + j] = s;
    G[(256 + j) * 512 + i] = s;
  }
}

// ---------------------------------------------------------------------------
// Kernel 3: left-looking diag step, NB=64.  One block, 256 threads.
// ---------------------------------------------------------------------------
__global__ __launch_bounds__(256) void chol_d64(float* __restrict__ G,
                                                float* __restrict__ Dinv,
                                                int p) {
  __shared__ float Pb[64][65];
  __shared__ float Sb[64][65];
  __shared__ float Inv[64][65];
  __shared__ float Tt[32][33];
  const int t = threadIdx.x;
  const int r0 = 64 * p;
  const int tr = (t >> 4) * 4, tc = (t & 15) * 4;

  for (int idx = t; idx < 4096; idx += 256) {
    int i = idx >> 6, j = idx & 63;
    float v = G[(long)(r0 + i) * 512 + r0 + j];
    if (i == j) v += EPSJ;
    Pb[i][j] = v;
  }
  __syncthreads();

  if (p > 0) {
    float cc[4][4] = {{0.f}};
    for (int r = 0; r < p; ++r) {
      for (int idx = t; idx < 4096; idx += 256) {
        int i = idx >> 6, j = idx & 63;
        Sb[i][j] = G[(long)(r0 + i) * 512 + 64 * r + j];
      }
      __syncthreads();
      #pragma unroll 4
      for (int k = 0; k < 64; ++k) {
        float a0 = Sb[tr][k], a1 = Sb[tr+1][k], a2 = Sb[tr+2][k], a3 = Sb[tr+3][k];
        float b0 = Sb[tc][k], b1 = Sb[tc+1][k], b2 = Sb[tc+2][k], b3 = Sb[tc+3][k];
        cc[0][0]+=a0*b0; cc[0][1]+=a0*b1; cc[0][2]+=a0*b2; cc[0][3]+=a0*b3;
        cc[1][0]+=a1*b0; cc[1][1]+=a1*b1; cc[1][2]+=a1*b2; cc[1][3]+=a1*b3;
        cc[2][0]+=a2*b0; cc[2][1]+=a2*b1; cc[2][2]+=a2*b2; cc[2][3]+=a2*b3;
        cc[3][0]+=a3*b0; cc[3][1]+=a3*b1; cc[3][2]+=a3*b2; cc[3][3]+=a3*b3;
      }
      __syncthreads();
    }
    #pragma unroll
    for (int u = 0; u < 4; ++u)
      #pragma unroll
      for (int v = 0; v < 4; ++v)
        Pb[tr + u][tc + v] -= cc[u][v];
    __syncthreads();
  }

  const int lane = t & 63, w = t >> 6;
  #pragma unroll
  for (int sp = 0; sp < 2; ++sp) {
    const int b0 = sp * 32;
    if (w == 0) {                       // 32-col register factor (proven)
      float rr[32];
      #pragma unroll
      for (int k = 0; k < 32; ++k)
        rr[k] = (lane < 32) ? Pb[b0 + lane][b0 + k] : 0.f;
      #pragma unroll
      for (int j = 0; j < 32; ++j) {
        float d = sqrtf(__shfl(rr[j], j));
        if (lane == j) rr[j] = d;
        else if (lane > j && lane < 32) rr[j] = rr[j] / d;
        float rj = rr[j];
        #pragma unroll
        for (int k = j + 1; k < 32; ++k) {
          float Lkj = __shfl(rj, k);
          if (lane > j && lane < 32) rr[k] -= rj * Lkj;
        }
      }
      #pragma unroll
      for (int k = 0; k < 32; ++k)
        if (lane < 32) Pb[b0 + lane][b0 + k] = rr[k];
    }
    __syncthreads();
    if (sp == 0) {
      if (t < 32) {                     // solve rows 32..63 vs A (proven)
        int rw = 32 + t;
        float x[32];
        #pragma unroll
        for (int j = 0; j < 32; ++j) x[j] = Pb[rw][j];
        #pragma unroll
        for (int j = 0; j < 32; ++j) {
          float xj = x[j] / Pb[j][j];
          x[j] = xj;
          #pragma unroll
          for (int k2 = j + 1; k2 < 32; ++k2) x[k2] -= xj * Pb[k2][j];
        }
        #pragma unroll
        for (int j = 0; j < 32; ++j) Pb[rw][j] = x[j];
      }
      __syncthreads();
      {                                 // trailing 32x32 -= S S^T
        int i = 32 + (t >> 3), kb = 32 + (t & 7) * 4;
        float sv[4];
        #pragma unroll
        for (int e = 0; e < 4; ++e) sv[e] = Pb[i][kb + e];
        #pragma unroll 4
        for (int j = 0; j < 32; ++j) {
          float aij = Pb[i][j];
          #pragma unroll
          for (int e = 0; e < 4; ++e) sv[e] -= aij * Pb[kb + e][j];
        }
        #pragma unroll
        for (int e = 0; e < 4; ++e) Pb[i][kb + e] = sv[e];
      }
      __syncthreads();
    }
  }

  // invert A (0..31) and C (32..63): 64 parallel column solves (x[32])
  if (t < 64) {
    int col = t & 31, o = (t >> 5) * 32;
    float x[32];
    #pragma unroll
    for (int i = 0; i < 32; ++i) {
      float s = (i == col) ? 1.f : 0.f;
      #pragma unroll
      for (int j = 0; j < i; ++j) s -= Pb[o + i][o + j] * x[j];
      x[i] = s / Pb[o + i][o + i];
    }
    #pragma unroll
    for (int i = 0; i < 32; ++i) Inv[o + i][o + col] = x[i];
  }
  for (int idx = t; idx < 1024; idx += 256)      // zero top-right quadrant
    Inv[idx >> 5][32 + (idx & 31)] = 0.f;
  __syncthreads();
  {                                              // T1 = B * A^{-1}
    int i = t >> 3, jb = (t & 7) * 4;
    float sv[4] = {0.f, 0.f, 0.f, 0.f};
    #pragma unroll 4
    for (int k = 0; k < 32; ++k) {
      float bik = Pb[32 + i][k];
      #pragma unroll
      for (int e = 0; e < 4; ++e) sv[e] += bik * Inv[k][jb + e];
    }
    #pragma unroll
    for (int e = 0; e < 4; ++e) Tt[i][jb + e] = sv[e];
  }
  __syncthreads();
  {                                              // BL = -C^{-1} * T1
    int i = t >> 3, jb = (t & 7) * 4;
    float sv[4] = {0.f, 0.f, 0.f, 0.f};
    #pragma unroll 4
    for (int k = 0; k < 32; ++k) {
      float cik = Inv[32 + i][32 + k];
      #pragma unroll
      for (int e = 0; e < 4; ++e) sv[e] += cik * Tt[k][jb + e];
    }
    #pragma unroll
    for (int e = 0; e < 4; ++e) Inv[32 + i][jb + e] = -sv[e];
  }
  __syncthreads();
  for (int idx = t; idx < 4096; idx += 256) {
    int i = idx >> 6, j = idx & 63;
    G[(long)(r0 + i) * 512 + r0 + j] = Pb[i][j];
    Dinv[p * 4096 + idx] = Inv[i][j];
  }
}

// ---------------------------------------------------------------------------
// Kernel 4: left-looking panel trsm-as-GEMM.  grid (7-p) x 256.
// ---------------------------------------------------------------------------
__global__ __launch_bounds__(256) void chol_t64(float* __restrict__ G,
                                                const float* __restrict__ Dinv,
                                                int p) {
  __shared__ float SbI[64][65];
  __shared__ float SbP[64][65];
  __shared__ float Ub[64][65];
  __shared__ float Db[64][65];
  const int t = threadIdx.x;
  const long rI = 64 * (p + 1 + blockIdx.x), cP = 64 * p;
  const int tr = (t >> 4) * 4, tc = (t & 15) * 4;

  for (int idx = t; idx < 4096; idx += 256)
    Db[idx >> 6][idx & 63] = Dinv[p * 4096 + idx];

  float cc[4][4] = {{0.f}};
  for (int r = 0; r < p; ++r) {
    __syncthreads();
    for (int idx = t; idx < 4096; idx += 256) {
      int i = idx >> 6, j = idx & 63;
      SbI[i][j] = G[(rI + i) * 512 + 64 * r + j];
      SbP[i][j] = G[(cP + i) * 512 + 64 * r + j];
    }
    __syncthreads();
    #pragma unroll 4
    for (int k = 0; k < 64; ++k) {
      float a0 = SbI[tr][k], a1 = SbI[tr+1][k], a2 = SbI[tr+2][k], a3 = SbI[tr+3][k];
      float b0 = SbP[tc][k], b1 = SbP[tc+1][k], b2 = SbP[tc+2][k], b3 = SbP[tc+3][k];
      cc[0][0]+=a0*b0; cc[0][1]+=a0*b1; cc[0][2]+=a0*b2; cc[0][3]+=a0*b3;
      cc[1][0]+=a1*b0; cc[1][1]+=a1*b1; cc[1][2]+=a1*b2; cc[1][3]+=a1*b3;
      cc[2][0]+=a2*b0; cc[2][1]+=a2*b1; cc[2][2]+=a2*b2; cc[2][3]+=a2*b3;
      cc[3][0]+=a3*b0; cc[3][1]+=a3*b1; cc[3][2]+=a3*b2; cc[3][3]+=a3*b3;
    }
  }
  __syncthreads();
  #pragma unroll
  for (int u = 0; u < 4; ++u)
    #pragma unroll
    for (int v = 0; v < 4; ++v)
      Ub[tr + u][tc + v] =
          G[(rI + tr + u) * 512 + cP + tc + v] - cc[u][v];
  __syncthreads();
  float xx[4][4] = {{0.f}};
  #pragma unroll 4
  for (int k = 0; k < 64; ++k) {
    float a0 = Ub[tr][k], a1 = Ub[tr+1][k], a2 = Ub[tr+2][k], a3 = Ub[tr+3][k];
    float b0 = Db[tc][k], b1 = Db[tc+1][k], b2 = Db[tc+2][k], b3 = Db[tc+3][k];
    xx[0][0]+=a0*b0; xx[0][1]+=a0*b1; xx[0][2]+=a0*b2; xx[0][3]+=a0*b3;
    xx[1][0]+=a1*b0; xx[1][1]+=a1*b1; xx[1][2]+=a1*b2; xx[1][3]+=a1*b3;
    xx[2][0]+=a2*b0; xx[2][1]+=a2*b1; xx[2][2]+=a2*b2; xx[2][3]+=a2*b3;
    xx[3][0]+=a3*b0; xx[3][1]+=a3*b1; xx[3][2]+=a3*b2; xx[3][3]+=a3*b3;
  }
  #pragma unroll
  for (int u = 0; u < 4; ++u)
    #pragma unroll
    for (int v = 0; v < 4; ++v)
      G[(rI + tr + u) * 512 + cP + tc + v] = xx[u][v];
}

// ---------------------------------------------------------------------------
// Kernel 5: blocked back-substitution -> PLAIN Wt (bf16, n-major), grid 8x256
// ---------------------------------------------------------------------------
__global__ __launch_bounds__(256) void tri_assemble(
    const float* __restrict__ G, const float* __restrict__ Dinv,
    unsigned short* __restrict__ Wt) {
  __shared__ float Bsh[448 * 64];   // rows for p>q, 112 KB
  __shared__ float T[64 * 64];      // 16 KB
  const int q = blockIdx.x, t = threadIdx.x;
  const int or_ = (t >> 4) * 4, oc = (t & 15) * 4;

  for (int p = q + 1; p < 8; ++p) {
    float cc[4][4] = {{0.f}};
    for (int r = q; r < p; ++r) {
      const float* Lbase = G + (long)(64 * p) * 512 + 64 * r;
      #pragma unroll 4
      for (int k = 0; k < 64; ++k) {
        float a0 = Lbase[(or_ + 0) * 512 + k];
        float a1 = Lbase[(or_ + 1) * 512 + k];
        float a2 = Lbase[(or_ + 2) * 512 + k];
        float a3 = Lbase[(or_ + 3) * 512 + k];
        float b0, b1, b2, b3;
        if (r == q) {
          const float* Bq = Dinv + q * 4096 + k * 64 + oc;
          b0 = Bq[0]; b1 = Bq[1]; b2 = Bq[2]; b3 = Bq[3];
        } else {
          const float* Br = Bsh + ((r - q - 1) * 64 + k) * 64 + oc;
          b0 = Br[0]; b1 = Br[1]; b2 = Br[2]; b3 = Br[3];
        }
        cc[0][0] += a0*b0; cc[0][1] += a0*b1; cc[0][2] += a0*b2; cc[0][3] += a0*b3;
        cc[1][0] += a1*b0; cc[1][1] += a1*b1; cc[1][2] += a1*b2; cc[1][3] += a1*b3;
        cc[2][0] += a2*b0; cc[2][1] += a2*b1; cc[2][2] += a2*b2; cc[2][3] += a2*b3;
        cc[3][0] += a3*b0; cc[3][1] += a3*b1; cc[3][2] += a3*b2; cc[3][3] += a3*b3;
      }
    }
    #pragma unroll
    for (int u = 0; u < 4; ++u)
      #pragma unroll
      for (int v = 0; v < 4; ++v)
        T[(or_ + u) * 64 + oc + v] = cc[u][v];
    __syncthreads();

    float c2[4][4] = {{0.f}};
    const float* Dp = Dinv + p * 4096;
    #pragma unroll 4
    for (int k = 0; k < 64; ++k) {
      float a0 = Dp[(or_ + 0) * 64 + k];
      float a1 = Dp[(or_ + 1) * 64 + k];
      float a2 = Dp[(or_ + 2) * 64 + k];
      float a3 = Dp[(or_ + 3) * 64 + k];
      const float* Tk = T + k * 64 + oc;
      float b0 = Tk[0], b1 = Tk[1], b2 = Tk[2], b3 = Tk[3];
      c2[0][0] += a0*b0; c2[0][1] += a0*b1; c2[0][2] += a0*b2; c2[0][3] += a0*b3;
      c2[1][0] += a1*b0; c2[1][1] += a1*b1; c2[1][2] += a1*b2; c2[1][3] += a1*b3;
      c2[2][0] += a2*b0; c2[2][1] += a2*b1; c2[2][2] += a2*b2; c2[2][3] += a2*b3;
      c2[3][0] += a3*b0; c2[3][1] += a3*b1; c2[3][2] += a3*b2; c2[3][3] += a3*b3;
    }
    #pragma unroll
    for (int u = 0; u < 4; ++u)
      #pragma unroll
      for (int v = 0; v < 4; ++v)
        Bsh[((p - q - 1) * 64 + or_ + u) * 64 + oc + v] = -c2[u][v];
    __syncthreads();
  }

  const int nr = (8 - q) * 64;
  for (int idx = t; idx < nr * 64; idx += 256) {
    int i = idx >> 6, kk = idx & 63;
    float v = (i < 64) ? Dinv[q * 4096 + i * 64 + kk]
                       : Bsh[(i - 64) * 64 + kk];
    int n = 64 * q + i;
    Wt[(long)n * 512 + 64 * q + kk] = f2bf(SQRTD * v);
  }
  for (int idx = t; idx < 64 * q * 64; idx += 256) {   // zeros above diagonal
    int n = idx >> 6, kk = idx & 63;
    Wt[(long)n * 512 + 64 * q + kk] = 0;
  }
}

// ---------------------------------------------------------------------------
// Kernel 6 (fast path): ymm7 = ymm4 geometry + counted-vmcnt pipeline.
// 512 thr (8 waves, 32x64 wave-tiles), A+B via global_load_lds dbuf with
// pre-swizzled per-lane sources (plain Wt).  XCD-bijective 1-D grid 8192.
// Loop: stage(next) -> vmcnt(4) [old tile landed, new 4 in flight] ->
// s_barrier -> compute -> lgkmcnt(0) -> s_barrier.  vmcnt never drained
// to 0 in the main loop.
// ---------------------------------------------------------------------------
__global__ __launch_bounds__(512, 4) void ymm7(
    const unsigned short* __restrict__ Xbf,
    const unsigned short* __restrict__ Wt, float* __restrict__ Y) {
  __shared__ unsigned short As[2][128 * 64];
  __shared__ unsigned short Bs[2][128 * 64];
  const int t = threadIdx.x, lane = t & 63, w = t >> 6;
  const int id = blockIdx.x;
  const int xcd = id & 7, j = id >> 3;
  const long m0 = (long)((j >> 2) * 8 + xcd) * 128;
  const int n0 = (j & 3) * 128;
  const int wm = (w >> 1) * 32, wn = (w & 1) * 64;
  f32x4 acc[2][4];
  const f32x4 zf = {0.f, 0.f, 0.f, 0.f};
  #pragma unroll
  for (int a = 0; a < 2; ++a)
    #pragma unroll
    for (int bq = 0; bq < 4; ++bq) acc[a][bq] = zf;

  auto stage = [&](int buf, int k0) {   // exactly 4 loads per thread
    #pragma unroll
    for (int h = 0; h < 2; ++h) {
      int seg = t + h * 512;
      int row = seg >> 3, sl = seg & 7;
      const unsigned short* sA =
          Xbf + (m0 + row) * 512 + k0 + swz(row, sl) * 8;
      const unsigned short* sB =
          Wt + (long)(n0 + row) * 512 + k0 + swz(row, sl) * 8;
      GLOAD16(sA, &As[buf][seg * 8]);
      GLOAD16(sB, &Bs[buf][seg * 8]);
    }
  };
  auto compute = [&](int buf) {
    #pragma unroll
    for (int kk = 0; kk < 2; ++kk) {
      bf16x8 af[2], bfr[4];
      #pragma unroll
      for (int fm = 0; fm < 2; ++fm) {
        int row = wm + fm * 16 + (lane & 15);
        af[fm] = *(const bf16x8*)((const char*)As[buf] + row * 128 +
                                  swz(row, kk * 4 + (lane >> 4)) * 16);
      }
      #pragma unroll
      for (int fn = 0; fn < 4; ++fn) {
        int row = wn + fn * 16 + (lane & 15);
        bfr[fn] = *(const bf16x8*)((const char*)Bs[buf] + row * 128 +
                                   swz(row, kk * 4 + (lane >> 4)) * 16);
      }
      #pragma unroll
      for (int fm = 0; fm < 2; ++fm)
        #pragma unroll
        for (int fn = 0; fn < 4; ++fn)
          acc[fm][fn] = __builtin_amdgcn_mfma_f32_16x16x32_bf16(
              bfr[fn], af[fm], acc[fm][fn], 0, 0, 0);   // swapped: reg axis = n
    }
  };

  stage(0, 0);
  asm volatile("s_waitcnt vmcnt(0)" ::: "memory");
  __builtin_amdgcn_s_barrier();
  int cur = 0;
  #pragma unroll 1
  for (int kt = 0; kt < 7; ++kt) {
    stage(cur ^ 1, (kt + 1) * 64);      // 4 new loads stay in flight
    asm volatile("s_waitcnt vmcnt(4)" ::: "memory");   // cur tile landed
    __builtin_amdgcn_s_barrier();
    compute(cur);
    asm volatile("s_waitcnt lgkmcnt(0)" ::: "memory"); // ds_reads returned
    __builtin_amdgcn_s_barrier();       // cur buf safe to re-stage
    cur ^= 1;
  }
  asm volatile("s_waitcnt vmcnt(0)" ::: "memory");
  __builtin_amdgcn_s_barrier();
  compute(cur);

  #pragma unroll
  for (int fm = 0; fm < 2; ++fm)
    #pragma unroll
    for (int fn = 0; fn < 4; ++fn) {
      long row = m0 + wm + fm * 16 + (lane & 15);
      int col = n0 + wn + fn * 16 + (lane >> 4) * 4;
      *(float4*)(Y + row * 512 + col) = *(float4*)&acc[fm][fn];
    }
}

// ---------------------------------------------------------------------------
// Kernel 6b (fallback): fp32 X reg-staged ymm, plain Wt.
// ---------------------------------------------------------------------------
__global__ __launch_bounds__(256) void ymm_v1(const float* __restrict__ X,
                                              const unsigned short* __restrict__ Wt,
                                              float* __restrict__ Y) {
  __shared__ unsigned short As[128 * 64];
  __shared__ unsigned short Bs[128 * 64];
  const int t = threadIdx.x, lane = t & 63, w = t >> 6;
  const long m0 = (long)blockIdx.x * 128;
  const int n0 = blockIdx.y * 128;
  const int wm = (w >> 1) * 64, wn = (w & 1) * 64;
  f32x4 acc[4][4];
  const f32x4 zf = {0.f, 0.f, 0.f, 0.f};
  #pragma unroll
  for (int a = 0; a < 4; ++a)
    #pragma unroll
    for (int bq = 0; bq < 4; ++bq) acc[a][bq] = zf;
  const int ko = t & 7, mrow = t >> 3;

  for (int k0 = 0; k0 < 512; k0 += 64) {
    #pragma unroll
    for (int it = 0; it < 4; ++it) {
      int m = mrow + 32 * it;
      const float4* src = (const float4*)(X + (m0 + m) * 512 + k0 + ko * 8);
      float4 f0 = src[0], f1 = src[1];
      unsigned p0 = (unsigned)f2bf(f0.x) | ((unsigned)f2bf(f0.y) << 16);
      unsigned p1 = (unsigned)f2bf(f0.z) | ((unsigned)f2bf(f0.w) << 16);
      unsigned p2 = (unsigned)f2bf(f1.x) | ((unsigned)f2bf(f1.y) << 16);
      unsigned p3 = (unsigned)f2bf(f1.z) | ((unsigned)f2bf(f1.w) << 16);
      int slot = swz(m, ko);
      *(uint4*)((char*)As + m * 128 + slot * 16) = make_uint4(p0, p1, p2, p3);
    }
    #pragma unroll
    for (int it = 0; it < 4; ++it) {
      int n = mrow + 32 * it;
      uint4 raw = *(const uint4*)(Wt + (long)(n0 + n) * 512 + k0 + ko * 8);
      int slot = swz(n, ko);
      *(uint4*)((char*)Bs + n * 128 + slot * 16) = raw;
    }
    __syncthreads();
    #pragma unroll
    for (int kk = 0; kk < 2; ++kk) {
      bf16x8 af[4], bfr[4];
      #pragma unroll
      for (int fm = 0; fm < 4; ++fm) {
        int row = wm + fm * 16 + (lane & 15);
        af[fm] = *(const bf16x8*)((const char*)As + row * 128 +
                                  swz(row, kk * 4 + (lane >> 4)) * 16);
      }
      #pragma unroll
      for (int fn = 0; fn < 4; ++fn) {
        int row = wn + fn * 16 + (lane & 15);
        bfr[fn] = *(const bf16x8*)((const char*)Bs + row * 128 +
                                   swz(row, kk * 4 + (lane >> 4)) * 16);
      }
      #pragma unroll
      for (int fm = 0; fm < 4; ++fm)
        #pragma unroll
        for (int fn = 0; fn < 4; ++fn)
          acc[fm][fn] = __builtin_amdgcn_mfma_f32_16x16x32_bf16(
              af[fm], bfr[fn], acc[fm][fn], 0, 0, 0);
    }
    __syncthreads();
  }
  #pragma unroll
  for (int fm = 0; fm < 4; ++fm)
    #pragma unroll
    for (int fn = 0; fn < 4; ++fn)
      #pragma unroll
      for (int j = 0; j < 4; ++j) {
        long row = m0 + wm + fm * 16 + (lane >> 4) * 4 + j;
        int col = n0 + wn + fn * 16 + (lane & 15);
        Y[row * 512 + col] = acc[fm][fn][j];
      }
}

// ---------------------------------------------------------------------------
static void chol_chain(float* G, float* Dinv, hipStream_t stream) {
  for (int p = 0; p < 8; ++p) {
    chol_d64<<<1, 256, 0, stream>>>(G, Dinv, p);
    if (p < 7) chol_t64<<<7 - p, 256, 0, stream>>>(G, Dinv, p);
  }
}

extern "C" void kernel_launch(void* const* d_in, const int* in_sizes, int n_in,
                              void* d_out, int out_size, void* d_ws, size_t ws_size,
                              hipStream_t stream) {
  const float* X = (const float*)d_in[0];
  float* Y = (float*)d_out;
  char* ws = (char*)d_ws;
  float* G = (float*)ws;                                     // 1 MiB fp32
  unsigned short* Wt = (unsigned short*)(ws + (1 << 20));    // 512 KiB bf16
  float* Dinv = (float*)(ws + (1 << 20) + (1 << 19));        // 128 KiB fp32

  const int NCH_FAST = 85;
  size_t part_off = (size_t)(2 << 20);
  size_t part_bytes = (size_t)NCH_FAST * 3 * 65536 * 4;      // 66.8 MB
  size_t xbf_off = part_off + part_bytes;
  size_t need = xbf_off + (size_t)134217728 * 2;             // + 256 MiB

  if (ws_size >= need) {
    float* part = (float*)(ws + part_off);
    unsigned short* Xbf = (unsigned short*)(ws + xbf_off);
    convert_bf<<<2048, 256, 0, stream>>>(X, Xbf);
    gram_bf<<<3 * NCH_FAST, 512, 0, stream>>>(Xbf, part, NCH_FAST);
    gram_reduce<<<768, 256, 0, stream>>>(part, G, NCH_FAST);
    chol_chain(G, Dinv, stream);
    tri_assemble<<<8, 256, 0, stream>>>(G, Dinv, Wt);
    ymm7<<<8192, 512, 0, stream>>>(Xbf, Wt, Y);
  } else {
    float* part = (float*)(ws + part_off);
    size_t fixed = part_off;
    int nchunk = 64;
    while (nchunk > 1 && fixed + (size_t)nchunk * 3 * 65536 * 4 > ws_size)
      nchunk >>= 1;
    gram_f32<<<3 * nchunk, 512, 0, stream>>>(X, part, nchunk);
    gram_reduce<<<768, 256, 0, stream>>>(part, G, nchunk);
    chol_chain(G, Dinv, stream);
    tri_assemble<<<8, 256, 0, stream>>>(G, Dinv, Wt);
    ymm_v1<<<dim3(2048, 4), 256, 0, stream>>>(X, Wt, Y);
  }
}